// Round 8
// baseline (5123.184 us; speedup 1.0000x reference)
//
#include <hip/hip_runtime.h>
#include <math.h>

#define DD   512
#define BATCH 128
#define NTOK 251
#define NHEAD 4
#define HD   128

#define GF_ADDC   1
#define GF_BIAS   2
#define GF_GELU   4
#define GF_OBF16  8
#define GF_LN     16

typedef unsigned short ushort_t;
typedef __attribute__((ext_vector_type(8))) short bf16x8;
typedef __attribute__((ext_vector_type(4))) float f32x4;

__constant__ int c_cols[3][12] = {
  {8,10,12,22,24,26, 9,11,13,23,25,27},
  {2, 4, 6,28,30,32, 3, 5, 7,29,31,33},
  {0,14,16,18,20, 1,15,17,19,21, 0, 0}
};
__constant__ int c_ncols[3] = {12,12,10};

__device__ __forceinline__ float gelu_f(float v){
  return 0.5f*v*(1.0f + erff(v*0.70710678118654752440f));
}
__device__ __forceinline__ ushort_t f2b(float v){   // RNE float->bf16
  union { float f; unsigned u; } x; x.f = v;
  unsigned r = x.u + 0x7fffu + ((x.u >> 16) & 1u);
  return (ushort_t)(r >> 16);
}
__device__ __forceinline__ float b2f(ushort_t u){
  union { unsigned u; float f; } x; x.u = ((unsigned)u) << 16; return x.f;
}
__device__ __forceinline__ void async_copy16(const void* g, void* l){
  __builtin_amdgcn_global_load_lds(
      (const __attribute__((address_space(1))) unsigned*)g,
      (__attribute__((address_space(3))) unsigned*)l, 16, 0, 0);
}

// ---- weight convert+transpose (head o1w only): D[n*ldD+k] = bf16(S[k*512+n]) ----
__global__ __launch_bounds__(256) void wtrans_kernel(ushort_t* __restrict__ dst,
                                                     const float* __restrict__ src,
                                                     long ldD, long dstPlane, long srcPlane){
  __shared__ float tile[32][33];
  long mat = blockIdx.z;
  const float* S = src + mat*srcPlane;
  ushort_t* D = dst + mat*dstPlane;
  int n0 = blockIdx.x*32, k0 = blockIdx.y*32;
  for (int r = threadIdx.y; r < 32; r += 8)
    tile[r][threadIdx.x] = S[(long)(k0+r)*DD + n0 + threadIdx.x];
  __syncthreads();
  for (int r = threadIdx.y; r < 32; r += 8)
    D[(long)(n0+r)*ldD + k0 + threadIdx.x] = f2b(tile[threadIdx.x][r]);
}

// ---- weight pack to MFMA-fragment order ----
// B2 layout: [nb (64-col block)][kc (0..15)][j (0..3)][lane (64)][8 bf16]
// lane=(quad<<4)|l15 holds Bt[n = nb*64 + j*16 + l15][k = kc*32 + quad*8 ..+8]
__global__ __launch_bounds__(256) void wpack_kernel(ushort_t* __restrict__ dst,
                                                    const float* __restrict__ src,
                                                    long dstPlane, long srcPlane){
  int c = blockIdx.x;                 // c = nb*16 + kc
  int nb = c >> 4, kc = c & 15;
  long mat = blockIdx.z;
  const float* S = src + mat*srcPlane;
  ushort_t* D = dst + mat*dstPlane + (long)c*2048;
  int t = threadIdx.x;
  int j = t >> 6, lane = t & 63;
  int quad = lane >> 4, l15 = lane & 15;
  int n = nb*64 + j*16 + l15;
  int k = kc*32 + quad*8;
  ushort_t o8[8];
  #pragma unroll
  for (int e = 0; e < 8; e++) o8[e] = f2b(S[(long)(k+e)*512 + n]);
  *(uint4*)(D + (j*64 + lane)*8) = *(const uint4*)o8;
}

// ---- embed -> bf16 h ----
__global__ void embed_kernel(ushort_t* __restrict__ h, const float* __restrict__ x,
                             const float* __restrict__ w, const float* __restrict__ bias,
                             const float* __restrict__ pos, const float* __restrict__ cls,
                             int br, int b0){
  long bt = blockIdx.x;
  int  t  = (int)(bt % NTOK);
  long b  = b0 + bt / NTOK;
  ushort_t* outr = h + bt*DD;
  if (t == 0){
    for (int d = threadIdx.x; d < DD; d += 128) outr[d] = f2b(cls[d] + pos[d]);
    return;
  }
  const float* xr = x + (b*(NTOK-1) + (t-1))*34;
  int nc = c_ncols[br];
  float xs[12];
  for (int j = 0; j < 12; j++) xs[j] = (j < nc) ? xr[c_cols[br][j]] : 0.0f;
  const float* posr = pos + (long)t*DD;
  for (int d = threadIdx.x; d < DD; d += 128){
    float acc = bias[d] + posr[d];
    for (int j = 0; j < nc; j++) acc = fmaf(xs[j], w[j*DD + d], acc);
    outr[d] = f2b(acc);
  }
}

// ---- V^T per (b,h): vt[plane][d][t] (ld 256, t-pad zeroed) ----
__global__ __launch_bounds__(256) void vtrans_kernel(ushort_t* __restrict__ vt,
                                                     const ushort_t* __restrict__ v){
  __shared__ ushort_t tile[32][33];
  int b = blockIdx.z >> 2, hh = blockIdx.z & 3;
  const ushort_t* src = v + (long)b*NTOK*1536 + hh*HD;
  ushort_t* dst = vt + (long)blockIdx.z*HD*256;
  int t0 = blockIdx.y*32, d0 = blockIdx.x*32;
  int tx = threadIdx.x, ty = threadIdx.y;
  for (int r = ty; r < 32; r += 8){
    int t = t0 + r;
    tile[r][tx] = (t < NTOK) ? src[(long)t*1536 + d0 + tx] : (ushort_t)0;
  }
  __syncthreads();
  for (int r = ty; r < 32; r += 8)
    dst[(long)(d0 + r)*256 + t0 + tx] = tile[tx][r];
}

// ---- fused flash attention, one block per (b,h) ----
__global__ __launch_bounds__(512, 2) void flash_kernel(
    ushort_t* __restrict__ o, const ushort_t* __restrict__ qkv,
    const ushort_t* __restrict__ vt, float alpha){
  // 16B "units": Ks[t][u], u=0..15 (row=256B); Vs[d][u], u=0..31 (row=512B)
  __shared__ __align__(16) ushort_t Ks[256*16*8];   // 64 KB
  __shared__ __align__(16) ushort_t Vs[128*32*8];   // 64 KB
  __shared__ __align__(16) ushort_t Ps[8][32*40];   // 20 KB, per-wave P
  int bh = blockIdx.x, b = bh>>2, hh = bh&3;
  const ushort_t* Qg = qkv + (long)b*NTOK*1536 + hh*HD;
  const ushort_t* Kg = Qg + 512;
  const ushort_t* Vg = vt + (long)bh*HD*256;
  int tid = threadIdx.x, w = tid>>6, lane = tid&63;
  int quad = lane>>4, l15 = lane&15;
  int swz = l15 & 7;

  bf16x8 qf[2][4];
  #pragma unroll
  for (int qs = 0; qs < 2; qs++){
    int qrow = w*32 + qs*16 + l15;
    bool qv = qrow < NTOK;
    const ushort_t* qptr = Qg + (long)qrow*1536;
    #pragma unroll
    for (int kc = 0; kc < 4; kc++)
      qf[qs][kc] = qv ? *(const bf16x8*)(qptr + kc*32 + quad*8)
                      : (bf16x8){0,0,0,0,0,0,0,0};
  }

  #pragma unroll
  for (int i = 0; i < 8; i++){
    int base = (w*8 + i)*64;
    int unit = base + lane;
    int t = unit >> 4, u = unit & 15;
    const ushort_t* src = Kg + (long)(t < NTOK ? t : 0)*1536 + ((u ^ (t&7)) << 3);
    async_copy16(src, (void*)&Ks[base*8]);
  }
  #pragma unroll
  for (int i = 0; i < 8; i++){
    int base = (w*8 + i)*64;
    int unit = base + lane;
    int d = unit >> 5, u = unit & 31;
    const ushort_t* src = Vg + (long)d*256 + ((u ^ (d&7)) << 3);
    async_copy16(src, (void*)&Vs[base*8]);
  }
  __syncthreads();

  f32x4 oacc[2][8] = {};
  float mrow[2][4], lrow[2][4];
  #pragma unroll
  for (int qs = 0; qs < 2; qs++)
    #pragma unroll
    for (int r = 0; r < 4; r++){ mrow[qs][r] = -1e30f; lrow[qs][r] = 0.0f; }

  ushort_t* Psw = &Ps[w][0];

  for (int c = 0; c < 8; c++){
    f32x4 s[2][2] = {};
    #pragma unroll
    for (int kc = 0; kc < 4; kc++){
      #pragma unroll
      for (int j = 0; j < 2; j++){
        int t = c*32 + j*16 + l15;
        bf16x8 bf = *(const bf16x8*)&Ks[(t*16 + ((kc*4 + quad) ^ swz))*8];
        s[0][j] = __builtin_amdgcn_mfma_f32_16x16x32_bf16(qf[0][kc], bf, s[0][j], 0, 0, 0);
        s[1][j] = __builtin_amdgcn_mfma_f32_16x16x32_bf16(qf[1][kc], bf, s[1][j], 0, 0, 0);
      }
    }
    #pragma unroll
    for (int qs = 0; qs < 2; qs++){
      #pragma unroll
      for (int r = 0; r < 4; r++){
        int t0 = c*32 + l15, t1 = t0 + 16;
        float v0 = (t0 < NTOK) ? s[qs][0][r]*alpha : -1e30f;
        float v1 = (t1 < NTOK) ? s[qs][1][r]*alpha : -1e30f;
        float mx = fmaxf(v0, v1);
        mx = fmaxf(mx, __shfl_xor(mx,1)); mx = fmaxf(mx, __shfl_xor(mx,2));
        mx = fmaxf(mx, __shfl_xor(mx,4)); mx = fmaxf(mx, __shfl_xor(mx,8));
        float Mn  = fmaxf(mrow[qs][r], mx);
        float fac = __expf(mrow[qs][r] - Mn);
        mrow[qs][r] = Mn;
        float e0 = __expf(v0 - Mn), e1 = __expf(v1 - Mn);
        float sum = e0 + e1;
        sum += __shfl_xor(sum,1); sum += __shfl_xor(sum,2);
        sum += __shfl_xor(sum,4); sum += __shfl_xor(sum,8);
        lrow[qs][r] = lrow[qs][r]*fac + sum;
        #pragma unroll
        for (int j = 0; j < 8; j++) oacc[qs][j][r] *= fac;
        Psw[(qs*16 + quad*4 + r)*40 + l15]      = f2b(e0);
        Psw[(qs*16 + quad*4 + r)*40 + 16 + l15] = f2b(e1);
      }
    }
    bf16x8 af0 = *(const bf16x8*)&Psw[(long)l15*40 + quad*8];
    bf16x8 af1 = *(const bf16x8*)&Psw[(long)(16 + l15)*40 + quad*8];
    #pragma unroll
    for (int j = 0; j < 8; j++){
      int d = j*16 + l15;
      bf16x8 bfv = *(const bf16x8*)&Vs[(d*32 + ((c*4 + quad) ^ swz))*8];
      oacc[0][j] = __builtin_amdgcn_mfma_f32_16x16x32_bf16(af0, bfv, oacc[0][j], 0, 0, 0);
      oacc[1][j] = __builtin_amdgcn_mfma_f32_16x16x32_bf16(af1, bfv, oacc[1][j], 0, 0, 0);
    }
  }

  #pragma unroll
  for (int qs = 0; qs < 2; qs++){
    #pragma unroll
    for (int r = 0; r < 4; r++){
      int q = w*32 + qs*16 + quad*4 + r;
      if (q >= NTOK) continue;
      float invl = 1.0f / lrow[qs][r];
      ushort_t* orow = o + ((long)b*NTOK + q)*512 + hh*128;
      #pragma unroll
      for (int j = 0; j < 8; j++)
        orow[j*16 + l15] = f2b(oacc[qs][j][r]*invl);
    }
  }
}

// ---- fused (optional LN) + row-panel GEMM, K=512 fixed, B in B2 pack ----
// 128-row A panel in LDS (128 KB, 1 block/CU — keeps per-XCD L2 write
// pressure ~2 MB; 64-row/2-block variant blew L2 and doubled HBM traffic).
// B staged per-kc through a 2x16KB LDS ping-pong via global_load_lds
// (2 DMA ops/thread/kc): DMA for kc+1 issues before compute of kc, the
// per-kc __syncthreads() drains it. No register B-pipeline for the
// compiler to collapse; buffer parity is compile-time (kc unrolled).
__global__ __launch_bounds__(512, 2) void lngemm_kernel(
    const ushort_t* __restrict__ A,          // [M][512] bf16
    const ushort_t* __restrict__ Bt,         // B2-packed weights
    void* __restrict__ Cp, long ldc,
    const float* __restrict__ lng, const float* __restrict__ lnbeta,
    const float* __restrict__ bias,
    int M, int N, int flags, float alpha){
  __shared__ __align__(16) ushort_t As[128*512];   // 128 KiB
  __shared__ __align__(16) ushort_t Bs[2][8192];   // 2 x 16 KiB ping-pong
  int tid = threadIdx.x, w = tid>>6, lane = tid&63;
  int quad = lane>>4, l15 = lane&15;
  int m0 = blockIdx.x*128;

  // per-thread B-staging slots (2 x 4KB chunks per kc, 16 wave-loads total)
  int nb0 = w >> 2,        jj0 = w & 3;          // chunk i=0: w
  int nb1 = (8 + w) >> 2,  jj1 = (8 + w) & 3;    // chunk i=1: 8+w
  long boff0 = (long)jj0*512 + lane*8;
  long boff1 = (long)jj1*512 + lane*8;

  // ---- stage A panel (swizzled source, linear dest) + B step 0 ----
  #pragma unroll
  for (int i = 0; i < 16; i++){
    int row = i*8 + w;
    int gr = m0 + row; if (gr >= M) gr = M - 1;
    const ushort_t* src = A + (long)gr*512 + ((lane ^ (row&7)) << 3);
    async_copy16(src, (void*)&As[row*512]);
  }
  {
    const ushort_t* s0 = Bt + (long)nb0*16*2048 + boff0;   // nt=0, kc=0
    const ushort_t* s1 = Bt + (long)nb1*16*2048 + boff1;
    async_copy16(s0, (void*)&Bs[0][nb0*2048 + jj0*512]);
    async_copy16(s1, (void*)&Bs[0][nb1*2048 + jj1*512]);
  }
  __syncthreads();

  // ---- optional LayerNorm in LDS (16 rows per wave) ----
  if (flags & GF_LN){
    const float* gp = lng + lane*8;
    const float* bp = lnbeta + lane*8;
    float4 g0 = *(const float4*)gp, g1 = *(const float4*)(gp+4);
    float4 e0 = *(const float4*)bp, e1 = *(const float4*)(bp+4);
    float gg[8] = {g0.x,g0.y,g0.z,g0.w,g1.x,g1.y,g1.z,g1.w};
    float bb[8] = {e0.x,e0.y,e0.z,e0.w,e1.x,e1.y,e1.z,e1.w};
    for (int j = 0; j < 16; j++){
      int r = w*16 + j;
      ushort_t* prow = &As[r*512 + ((lane ^ (r&7)) << 3)];
      union { uint4 v; ushort_t s[8]; } raw;
      raw.v = *(const uint4*)prow;
      float d[8];
      #pragma unroll
      for (int e = 0; e < 8; e++) d[e] = b2f(raw.s[e]);
      float s = 0.0f;
      #pragma unroll
      for (int e = 0; e < 8; e++) s += d[e];
      #pragma unroll
      for (int o = 32; o > 0; o >>= 1) s += __shfl_xor(s, o, 64);
      float mu = s * (1.0f/512.0f);
      float q = 0.0f;
      #pragma unroll
      for (int e = 0; e < 8; e++){ d[e] -= mu; q += d[e]*d[e]; }
      #pragma unroll
      for (int o = 32; o > 0; o >>= 1) q += __shfl_xor(q, o, 64);
      float rr = rsqrtf(q*(1.0f/512.0f) + 1e-5f);
      ushort_t o8[8];
      #pragma unroll
      for (int e = 0; e < 8; e++) o8[e] = f2b(d[e]*rr*gg[e] + bb[e]);
      *(uint4*)prow = *(const uint4*)o8;
    }
  }
  __syncthreads();

  // ---- compute: wave tile 64x64, 256-col slabs; nb = nt*4 + (w&3) ----
  int wm = (w>>2)*64, nbw = w & 3;
  int NT = N >> 8;
  for (int nt = 0; nt < NT; nt++){
    f32x4 acc[4][4] = {};
    #pragma unroll
    for (int kc = 0; kc < 16; kc++){
      // prefetch step (nt,kc)+1 into parity (kc+1)&1
      int ntp, kcp;
      if (kc < 15){ ntp = nt; kcp = kc + 1; }
      else { bool more = (nt + 1 < NT); ntp = more ? nt + 1 : nt; kcp = more ? 0 : 15; }
      {
        const ushort_t* s0 = Bt + ((long)(ntp*4 + nb0)*16 + kcp)*2048 + boff0;
        const ushort_t* s1 = Bt + ((long)(ntp*4 + nb1)*16 + kcp)*2048 + boff1;
        async_copy16(s0, (void*)&Bs[(kc+1)&1][nb0*2048 + jj0*512]);
        async_copy16(s1, (void*)&Bs[(kc+1)&1][nb1*2048 + jj1*512]);
      }
      // compute kc from Bs[kc&1]
      const ushort_t* Bp = &Bs[kc&1][nbw*2048];
      bf16x8 af[4], bv[4];
      #pragma unroll
      for (int i = 0; i < 4; i++){
        int row = wm + i*16 + l15;
        af[i] = *(const bf16x8*)&As[row*512 + (((kc*4+quad) ^ (row&7)) << 3)];
      }
      #pragma unroll
      for (int j = 0; j < 4; j++)
        bv[j] = *(const bf16x8*)(Bp + (long)j*512 + lane*8);
      #pragma unroll
      for (int i = 0; i < 4; i++)
        #pragma unroll
        for (int j = 0; j < 4; j++)
          acc[i][j] = __builtin_amdgcn_mfma_f32_16x16x32_bf16(af[i], bv[j], acc[i][j], 0, 0, 0);
      __syncthreads();   // drains DMA for kc+1; orders buffer reuse
    }
    // epilogue: C/D layout col=lane&15, row=quad*4+reg
    #pragma unroll
    for (int i = 0; i < 4; i++){
      int rbase = m0 + wm + i*16 + quad*4;
      #pragma unroll
      for (int j = 0; j < 4; j++){
        int gn = nt*256 + nbw*64 + j*16 + l15;
        #pragma unroll
        for (int r = 0; r < 4; r++){
          int gm = rbase + r;
          if (gm >= M) continue;
          float v = acc[i][j][r] * alpha;
          if (flags & GF_BIAS) v += bias[gn];
          if (flags & GF_ADDC) v += b2f(((const ushort_t*)Cp)[(long)gm*ldc + gn]);
          if (flags & GF_GELU) v = gelu_f(v);
          if (flags & GF_OBF16) ((ushort_t*)Cp)[(long)gm*ldc + gn] = f2b(v);
          else                  ((float*)Cp)[(long)gm*ldc + gn] = v;
        }
      }
    }
  }
}

// ---- MFMA GEMM (head only): C = alpha*A[M,K] @ Bt[N,K]^T ----
__global__ __launch_bounds__(256) void gemm_bt_mfma(
    const ushort_t* __restrict__ A, long lda, long sA1, long sA2,
    const ushort_t* __restrict__ Bt, long ldb, long sB1, long sB2,
    void* __restrict__ Cp, long ldc, long sC1, long sC2,
    const float* __restrict__ bias, int M, int N, int K,
    int zdiv, int flags, float alpha){
  int bz = blockIdx.z;
  A  += (long)(bz/zdiv)*sA1 + (long)(bz%zdiv)*sA2;
  Bt += (long)(bz/zdiv)*sB1 + (long)(bz%zdiv)*sB2;
  long coff = (long)(bz/zdiv)*sC1 + (long)(bz%zdiv)*sC2;

  __shared__ __align__(16) ushort_t As[128*32];
  __shared__ __align__(16) ushort_t Bs[128*32];

  int tid = threadIdx.x;
  int wave = tid >> 6, lane = tid & 63;
  int quad = lane >> 4, l15 = lane & 15;
  int wm = (wave >> 1) * 64, wn = (wave & 1) * 64;
  int m0 = blockIdx.y * 128, n0 = blockIdx.x * 128;

  f32x4 acc[4][4] = {};
  bool fast = (m0 + 128 <= M) && (n0 + 128 <= N) && ((K & 31) == 0);

  if (fast){
    int rloc = wave*16 + (lane >> 2);
    int pos  = lane & 3;
    const ushort_t* A0 = A + (long)m0*lda;
    const ushort_t* B0 = Bt + (long)n0*ldb;
    for (int k0 = 0; k0 < K; k0 += 32){
      #pragma unroll
      for (int c = 0; c < 2; c++){
        int r  = c*64 + rloc;
        int cg = pos ^ ((r >> 1) & 3);
        long koff = k0 + cg*8;
        async_copy16(A0 + (long)r*lda + koff, (void*)&As[(c*256 + wave*64)*8]);
        async_copy16(B0 + (long)r*ldb + koff, (void*)&Bs[(c*256 + wave*64)*8]);
      }
      __syncthreads();
      bf16x8 af[4], bfv[4];
      #pragma unroll
      for (int i = 0; i < 4; i++){
        int row = wm + i*16 + l15;
        af[i] = *(const bf16x8*)&As[row*32 + ((quad ^ ((row>>1)&3)) << 3)];
      }
      #pragma unroll
      for (int j = 0; j < 4; j++){
        int row = wn + j*16 + l15;
        bfv[j] = *(const bf16x8*)&Bs[row*32 + ((quad ^ ((row>>1)&3)) << 3)];
      }
      #pragma unroll
      for (int i = 0; i < 4; i++)
        #pragma unroll
        for (int j = 0; j < 4; j++)
          acc[i][j] = __builtin_amdgcn_mfma_f32_16x16x32_bf16(af[i], bfv[j], acc[i][j], 0, 0, 0);
      __syncthreads();
    }
  } else {
    int nk = (K + 31) >> 5;
    for (int kt = 0; kt < nk; kt++){
      int k0 = kt << 5;
      #pragma unroll
      for (int c = 0; c < 2; c++){
        int q = c*256 + tid;
        int r = q >> 2;
        int gk = k0 + (((q & 3) ^ ((r >> 1) & 3)) << 3);
        {
          int gm = m0 + r;
          uint4 va;
          if (gm < M && gk + 8 <= K){
            va = *(const uint4*)(A + (long)gm*lda + gk);
          } else {
            ushort_t t[8];
            #pragma unroll
            for (int e = 0; e < 8; e++){
              int kk = gk + e;
              t[e] = (gm < M && kk < K) ? A[(long)gm*lda + kk] : (ushort_t)0;
            }
            va = *(const uint4*)t;
          }
          *(uint4*)&As[r*32 + (q & 3)*8] = va;
        }
        {
          int gn = n0 + r;
          uint4 vb;
          if (gn < N && gk + 8 <= K){
            vb = *(const uint4*)(Bt + (long)gn*ldb + gk);
          } else {
            ushort_t t[8];
            #pragma unroll
            for (int e = 0; e < 8; e++){
              int kk = gk + e;
              t[e] = (gn < N && kk < K) ? Bt[(long)gn*ldb + kk] : (ushort_t)0;
            }
            vb = *(const uint4*)t;
          }
          *(uint4*)&Bs[r*32 + (q & 3)*8] = vb;
        }
      }
      __syncthreads();
      bf16x8 af[4], bfv[4];
      #pragma unroll
      for (int i = 0; i < 4; i++){
        int row = wm + i*16 + l15;
        af[i] = *(const bf16x8*)&As[row*32 + ((quad ^ ((row>>1)&3)) << 3)];
      }
      #pragma unroll
      for (int j = 0; j < 4; j++){
        int row = wn + j*16 + l15;
        bfv[j] = *(const bf16x8*)&Bs[row*32 + ((quad ^ ((row>>1)&3)) << 3)];
      }
      #pragma unroll
      for (int i = 0; i < 4; i++)
        #pragma unroll
        for (int j = 0; j < 4; j++)
          acc[i][j] = __builtin_amdgcn_mfma_f32_16x16x32_bf16(af[i], bfv[j], acc[i][j], 0, 0, 0);
      __syncthreads();
    }
  }

  #pragma unroll
  for (int i = 0; i < 4; i++){
    int rbase = m0 + wm + i*16 + quad*4;
    #pragma unroll
    for (int j = 0; j < 4; j++){
      int gn = n0 + wn + j*16 + l15;
      if (gn >= N) continue;
      #pragma unroll
      for (int r = 0; r < 4; r++){
        int gm = rbase + r;
        if (gm >= M) continue;
        float v = acc[i][j][r] * alpha;
        if (flags & GF_BIAS) v += bias[gn];
        if (flags & GF_ADDC){
          if (flags & GF_OBF16) v += b2f(((const ushort_t*)Cp)[coff + (long)gm*ldc + gn]);
          else                  v += ((const float*)Cp)[coff + (long)gm*ldc + gn];
        }
        if (flags & GF_GELU) v = gelu_f(v);
        if (flags & GF_OBF16){
          ((ushort_t*)Cp)[coff + (long)gm*ldc + gn] = f2b(v);
        } else {
          ((float*)Cp)[coff + (long)gm*ldc + gn] = v;
        }
      }
    }
  }
}

__global__ void copy_cls(ushort_t* __restrict__ cat, const ushort_t* __restrict__ h,
                         int br, int b0){
  long b = blockIdx.x;
  int d = threadIdx.x;            // block 512
  cat[(b0+b)*1536 + (long)br*512 + d] = h[b*(long)NTOK*DD + d];
}

__global__ void head2_kernel(float* __restrict__ out, const float* __restrict__ hid,
                             const float* __restrict__ w2, const float* __restrict__ b2){
  __shared__ float sbuf[8];
  long b = blockIdx.x;
  float v = hid[b*DD + threadIdx.x] * w2[threadIdx.x];   // block 512
  #pragma unroll
  for (int o = 32; o > 0; o >>= 1) v += __shfl_down(v, o, 64);
  if ((threadIdx.x & 63) == 0) sbuf[threadIdx.x>>6] = v;
  __syncthreads();
  if (threadIdx.x == 0){
    float s = 0.0f;
    #pragma unroll
    for (int i = 0; i < 8; i++) s += sbuf[i];
    out[b] = 1.0f/(1.0f + expf(-(s + b2[0])));
  }
}

static size_t ws_needed(int Bc){
  auto al = [](size_t b){ return ((b + 255)/256)*256; };
  size_t BNc = (size_t)Bc*NTOK;
  size_t tot = 0;
  tot += al((12UL*1536 + 36UL*512 + 512UL)*512*2 + 512UL*1024*2); // bf16 weights (+o1)
  tot += al(BNc*DD*2);                        // h bf16 (residual)
  tot += al(BNc*DD*2);                        // z bf16
  tot += al(BNc*1536*2);                      // qkv bf16
  tot += al((size_t)Bc*NHEAD*HD*256*2);       // vt
  tot += al(128UL*1536*2) + al(128UL*512*4);  // cat bf16, hid fp32
  tot += 4096;
  return tot;
}

extern "C" void kernel_launch(void* const* d_in, const int* in_sizes, int n_in,
                              void* d_out, int out_size, void* d_ws, size_t ws_size,
                              hipStream_t stream){
  (void)in_sizes; (void)n_in; (void)out_size;
  const float* x      = (const float*)d_in[0];
  const float* w_left = (const float*)d_in[1];
  const float* b_left = (const float*)d_in[2];
  const float* w_right= (const float*)d_in[3];
  const float* b_right= (const float*)d_in[4];
  const float* w_mid  = (const float*)d_in[5];
  const float* b_mid  = (const float*)d_in[6];
  const float* pos    = (const float*)d_in[7];
  const float* cls    = (const float*)d_in[8];
  const float* ln1_g  = (const float*)d_in[9];
  const float* ln1_b  = (const float*)d_in[10];
  const float* ln2_g  = (const float*)d_in[11];
  const float* ln2_b  = (const float*)d_in[12];
  const float* wq     = (const float*)d_in[13];
  const float* wk     = (const float*)d_in[14];
  const float* wv     = (const float*)d_in[15];
  const float* wo     = (const float*)d_in[16];
  const float* fc1w   = (const float*)d_in[17];
  const float* fc1b   = (const float*)d_in[18];
  const float* fc2w   = (const float*)d_in[19];
  const float* fc2b   = (const float*)d_in[20];
  const float* o1w    = (const float*)d_in[21];
  const float* o1b    = (const float*)d_in[22];
  const float* o2w    = (const float*)d_in[23];
  const float* o2b    = (const float*)d_in[24];
  float* out = (float*)d_out;

  int Bc = 128;
  while (Bc > 1 && ws_needed(Bc) > ws_size) Bc >>= 1;
  const int nchunk = BATCH / Bc;
  const long BNc  = (long)Bc*NTOK;

  char* wsp = (char*)d_ws;
  auto carveb = [&](size_t bytes)->void*{
    void* p = (void*)wsp;
    wsp += ((bytes + 255)/256)*256;
    return p;
  };
  ushort_t* wt   = (ushort_t*)carveb((12UL*1536 + 36UL*512 + 512UL)*512*2 + 512UL*1024*2);
  ushort_t* h    = (ushort_t*)carveb(BNc*DD*2);
  ushort_t* z    = (ushort_t*)carveb(BNc*DD*2);
  ushort_t* qkv  = (ushort_t*)carveb(BNc*1536*2);
  ushort_t* vt   = (ushort_t*)carveb((size_t)Bc*NHEAD*HD*256*2);
  ushort_t* cat  = (ushort_t*)carveb(128UL*1536*2);
  float*    hid  = (float*)   carveb(128UL*512*4);

  ushort_t* wtqkv = wt;                     // B2 pack: [layer][nb24][kc][j][lane][8]
  ushort_t* wto   = wt + 12UL*1536*512;     // B2 pack: [layer][nb8][...]
  ushort_t* wt1   = wto + 12UL*512*512;
  ushort_t* wt2   = wt1 + 12UL*512*512;
  ushort_t* wth   = wt2 + 12UL*512*512;     // o1w^T: [512][1536] (row-major, head)

  {
    // B2 fragment-order pack (12 planes each). QKV interleaved per layer:
    // layer stride 1536*512; Q at nb 0..7, K at nb 8..15, V at nb 16..23.
    dim3 gp(128, 1, 12), bp(256);
    long dpq = 1536L*512, dps = 512L*512;
    wpack_kernel<<<gp,bp,0,stream>>>(wtqkv,              wq,   dpq, dps);
    wpack_kernel<<<gp,bp,0,stream>>>(wtqkv + 8L*32768,   wk,   dpq, dps);
    wpack_kernel<<<gp,bp,0,stream>>>(wtqkv + 16L*32768,  wv,   dpq, dps);
    wpack_kernel<<<gp,bp,0,stream>>>(wto,                wo,   dps, dps);
    wpack_kernel<<<gp,bp,0,stream>>>(wt1,                fc1w, dps, dps);
    wpack_kernel<<<gp,bp,0,stream>>>(wt2,                fc2w, dps, dps);
    wtrans_kernel<<<dim3(16,48,1),dim3(32,8),0,stream>>>(wth, o1w, 1536, 0, 0);
  }

  const float* wsel[3] = {w_left, w_right, w_mid};
  const float* bsel[3] = {b_left, b_right, b_mid};

  const float alpha = 0.08838834764831845f;  // 1/sqrt(128)
  int mt = (int)((BNc + 127)/128);
  dim3 gpanel(mt, 1, 1);
  dim3 gvt(4, 8, Bc*NHEAD);

  for (int br = 0; br < 3; br++){
    for (int c = 0; c < nchunk; c++){
      int b0 = c*Bc;
      embed_kernel<<<(int)BNc, 128, 0, stream>>>(h, x, wsel[br], bsel[br], pos, cls, br, b0);
      for (int l = 0; l < 4; l++){
        long wi = (long)br*4 + l;
        const float* g1 = ln1_g + wi*DD; const float* be1 = ln1_b + wi*DD;
        const float* g2 = ln2_g + wi*DD; const float* be2 = ln2_b + wi*DD;
        const ushort_t* Wqkv = wtqkv + wi*1536*512;
        const ushort_t* Wo   = wto + wi*DD*DD;
        const ushort_t* F1   = wt1 + wi*DD*DD;
        const ushort_t* F2   = wt2 + wi*DD*DD;
        const float* F1b = fc1b + wi*DD;  const float* F2b = fc2b + wi*DD;

        // qkv = LN1(h) @ Wqkv^T     (LN fused into A-panel staging)
        lngemm_kernel<<<gpanel, 512, 0, stream>>>(h, Wqkv, qkv, 1536, g1, be1,
                                                  nullptr, (int)BNc, 1536,
                                                  GF_LN|GF_OBF16, 1.0f);
        vtrans_kernel<<<gvt, dim3(32,8), 0, stream>>>(vt, qkv + 1024);
        flash_kernel<<<dim3(Bc*NHEAD), dim3(512), 0, stream>>>(z, qkv, vt, alpha);
        // h += z @ Wo^T
        lngemm_kernel<<<gpanel, 512, 0, stream>>>(z, Wo, h, 512, nullptr, nullptr,
                                                  nullptr, (int)BNc, 512,
                                                  GF_ADDC|GF_OBF16, 1.0f);
        // m = gelu(LN2(h) @ F1^T + b1)   -> qkv buffer
        lngemm_kernel<<<gpanel, 512, 0, stream>>>(h, F1, qkv, 512, g2, be2,
                                                  F1b, (int)BNc, 512,
                                                  GF_LN|GF_BIAS|GF_GELU|GF_OBF16, 1.0f);
        // h += m @ F2^T + b2
        lngemm_kernel<<<gpanel, 512, 0, stream>>>(qkv, F2, h, 512, nullptr, nullptr,
                                                  F2b, (int)BNc, 512,
                                                  GF_BIAS|GF_ADDC|GF_OBF16, 1.0f);
      }
      copy_cls<<<Bc, 512, 0, stream>>>(cat, h, br, b0);
    }
  }
  // head: hid = gelu(cat @ o1w + o1b) via MFMA (M=128,N=512,K=1536), then head2
  dim3 ghd(4, 1, 1);
  gemm_bt_mfma<<<ghd, dim3(256), 0, stream>>>(cat,1536,0,0, wth,1536,0,0, hid,DD,0,0, o1b,
                                              128,DD,1536, 1, GF_BIAS|GF_GELU, 1.0f);
  head2_kernel<<<BATCH, 512, 0, stream>>>(out, hid, o2w, o2b);
}

// Round 11
// 4912.949 us; speedup vs baseline: 1.0428x; 1.0428x over previous
//
#include <hip/hip_runtime.h>
#include <math.h>

#define DD   512
#define BATCH 128
#define NTOK 251
#define NHEAD 4
#define HD   128

#define GF_ADDC   1
#define GF_BIAS   2
#define GF_GELU   4
#define GF_OBF16  8
#define GF_LN     16

typedef unsigned short ushort_t;
typedef __attribute__((ext_vector_type(8))) short bf16x8;
typedef __attribute__((ext_vector_type(4))) float f32x4;

__constant__ int c_cols[3][12] = {
  {8,10,12,22,24,26, 9,11,13,23,25,27},
  {2, 4, 6,28,30,32, 3, 5, 7,29,31,33},
  {0,14,16,18,20, 1,15,17,19,21, 0, 0}
};
__constant__ int c_ncols[3] = {12,12,10};

__device__ __forceinline__ float gelu_f(float v){
  return 0.5f*v*(1.0f + erff(v*0.70710678118654752440f));
}
__device__ __forceinline__ ushort_t f2b(float v){   // RNE float->bf16
  union { float f; unsigned u; } x; x.f = v;
  unsigned r = x.u + 0x7fffu + ((x.u >> 16) & 1u);
  return (ushort_t)(r >> 16);
}
__device__ __forceinline__ float b2f(ushort_t u){
  union { unsigned u; float f; } x; x.u = ((unsigned)u) << 16; return x.f;
}
__device__ __forceinline__ void async_copy16(const void* g, void* l){
  __builtin_amdgcn_global_load_lds(
      (const __attribute__((address_space(1))) unsigned*)g,
      (__attribute__((address_space(3))) unsigned*)l, 16, 0, 0);
}

// ---- weight convert+transpose (head o1w only): D[n*ldD+k] = bf16(S[k*512+n]) ----
__global__ __launch_bounds__(256) void wtrans_kernel(ushort_t* __restrict__ dst,
                                                     const float* __restrict__ src,
                                                     long ldD, long dstPlane, long srcPlane){
  __shared__ float tile[32][33];
  long mat = blockIdx.z;
  const float* S = src + mat*srcPlane;
  ushort_t* D = dst + mat*dstPlane;
  int n0 = blockIdx.x*32, k0 = blockIdx.y*32;
  for (int r = threadIdx.y; r < 32; r += 8)
    tile[r][threadIdx.x] = S[(long)(k0+r)*DD + n0 + threadIdx.x];
  __syncthreads();
  for (int r = threadIdx.y; r < 32; r += 8)
    D[(long)(n0+r)*ldD + k0 + threadIdx.x] = f2b(tile[threadIdx.x][r]);
}

// ---- weight pack to MFMA-fragment order ----
// B2 layout: [nb (64-col block)][kc (0..15)][j (0..3)][lane (64)][8 bf16]
// lane=(quad<<4)|l15 holds Bt[n = nb*64 + j*16 + l15][k = kc*32 + quad*8 ..+8]
__global__ __launch_bounds__(256) void wpack_kernel(ushort_t* __restrict__ dst,
                                                    const float* __restrict__ src,
                                                    long dstPlane, long srcPlane){
  int c = blockIdx.x;                 // c = nb*16 + kc
  int nb = c >> 4, kc = c & 15;
  long mat = blockIdx.z;
  const float* S = src + mat*srcPlane;
  ushort_t* D = dst + mat*dstPlane + (long)c*2048;
  int t = threadIdx.x;
  int j = t >> 6, lane = t & 63;
  int quad = lane >> 4, l15 = lane & 15;
  int n = nb*64 + j*16 + l15;
  int k = kc*32 + quad*8;
  ushort_t o8[8];
  #pragma unroll
  for (int e = 0; e < 8; e++) o8[e] = f2b(S[(long)(k+e)*512 + n]);
  *(uint4*)(D + (j*64 + lane)*8) = *(const uint4*)o8;
}

// ---- embed -> bf16 h ----
__global__ void embed_kernel(ushort_t* __restrict__ h, const float* __restrict__ x,
                             const float* __restrict__ w, const float* __restrict__ bias,
                             const float* __restrict__ pos, const float* __restrict__ cls,
                             int br, int b0){
  long bt = blockIdx.x;
  int  t  = (int)(bt % NTOK);
  long b  = b0 + bt / NTOK;
  ushort_t* outr = h + bt*DD;
  if (t == 0){
    for (int d = threadIdx.x; d < DD; d += 128) outr[d] = f2b(cls[d] + pos[d]);
    return;
  }
  const float* xr = x + (b*(NTOK-1) + (t-1))*34;
  int nc = c_ncols[br];
  float xs[12];
  for (int j = 0; j < 12; j++) xs[j] = (j < nc) ? xr[c_cols[br][j]] : 0.0f;
  const float* posr = pos + (long)t*DD;
  for (int d = threadIdx.x; d < DD; d += 128){
    float acc = bias[d] + posr[d];
    for (int j = 0; j < nc; j++) acc = fmaf(xs[j], w[j*DD + d], acc);
    outr[d] = f2b(acc);
  }
}

// ---- V^T per (b,h): vt[plane][d][t] (ld 256, t-pad zeroed) ----
__global__ __launch_bounds__(256) void vtrans_kernel(ushort_t* __restrict__ vt,
                                                     const ushort_t* __restrict__ v){
  __shared__ ushort_t tile[32][33];
  int b = blockIdx.z >> 2, hh = blockIdx.z & 3;
  const ushort_t* src = v + (long)b*NTOK*1536 + hh*HD;
  ushort_t* dst = vt + (long)blockIdx.z*HD*256;
  int t0 = blockIdx.y*32, d0 = blockIdx.x*32;
  int tx = threadIdx.x, ty = threadIdx.y;
  for (int r = ty; r < 32; r += 8){
    int t = t0 + r;
    tile[r][tx] = (t < NTOK) ? src[(long)t*1536 + d0 + tx] : (ushort_t)0;
  }
  __syncthreads();
  for (int r = ty; r < 32; r += 8)
    dst[(long)(d0 + r)*256 + t0 + tx] = tile[tx][r];
}

// ---- fused flash attention, one block per (b,h) ----
__global__ __launch_bounds__(512, 2) void flash_kernel(
    ushort_t* __restrict__ o, const ushort_t* __restrict__ qkv,
    const ushort_t* __restrict__ vt, float alpha){
  // 16B "units": Ks[t][u], u=0..15 (row=256B); Vs[d][u], u=0..31 (row=512B)
  __shared__ __align__(16) ushort_t Ks[256*16*8];   // 64 KB
  __shared__ __align__(16) ushort_t Vs[128*32*8];   // 64 KB
  __shared__ __align__(16) ushort_t Ps[8][32*40];   // 20 KB, per-wave P
  int bh = blockIdx.x, b = bh>>2, hh = bh&3;
  const ushort_t* Qg = qkv + (long)b*NTOK*1536 + hh*HD;
  const ushort_t* Kg = Qg + 512;
  const ushort_t* Vg = vt + (long)bh*HD*256;
  int tid = threadIdx.x, w = tid>>6, lane = tid&63;
  int quad = lane>>4, l15 = lane&15;
  int swz = l15 & 7;

  bf16x8 qf[2][4];
  #pragma unroll
  for (int qs = 0; qs < 2; qs++){
    int qrow = w*32 + qs*16 + l15;
    bool qv = qrow < NTOK;
    const ushort_t* qptr = Qg + (long)qrow*1536;
    #pragma unroll
    for (int kc = 0; kc < 4; kc++)
      qf[qs][kc] = qv ? *(const bf16x8*)(qptr + kc*32 + quad*8)
                      : (bf16x8){0,0,0,0,0,0,0,0};
  }

  #pragma unroll
  for (int i = 0; i < 8; i++){
    int base = (w*8 + i)*64;
    int unit = base + lane;
    int t = unit >> 4, u = unit & 15;
    const ushort_t* src = Kg + (long)(t < NTOK ? t : 0)*1536 + ((u ^ (t&7)) << 3);
    async_copy16(src, (void*)&Ks[base*8]);
  }
  #pragma unroll
  for (int i = 0; i < 8; i++){
    int base = (w*8 + i)*64;
    int unit = base + lane;
    int d = unit >> 5, u = unit & 31;
    const ushort_t* src = Vg + (long)d*256 + ((u ^ (d&7)) << 3);
    async_copy16(src, (void*)&Vs[base*8]);
  }
  __syncthreads();

  f32x4 oacc[2][8] = {};
  float mrow[2][4], lrow[2][4];
  #pragma unroll
  for (int qs = 0; qs < 2; qs++)
    #pragma unroll
    for (int r = 0; r < 4; r++){ mrow[qs][r] = -1e30f; lrow[qs][r] = 0.0f; }

  ushort_t* Psw = &Ps[w][0];

  for (int c = 0; c < 8; c++){
    f32x4 s[2][2] = {};
    #pragma unroll
    for (int kc = 0; kc < 4; kc++){
      #pragma unroll
      for (int j = 0; j < 2; j++){
        int t = c*32 + j*16 + l15;
        bf16x8 bf = *(const bf16x8*)&Ks[(t*16 + ((kc*4 + quad) ^ swz))*8];
        s[0][j] = __builtin_amdgcn_mfma_f32_16x16x32_bf16(qf[0][kc], bf, s[0][j], 0, 0, 0);
        s[1][j] = __builtin_amdgcn_mfma_f32_16x16x32_bf16(qf[1][kc], bf, s[1][j], 0, 0, 0);
      }
    }
    #pragma unroll
    for (int qs = 0; qs < 2; qs++){
      #pragma unroll
      for (int r = 0; r < 4; r++){
        int t0 = c*32 + l15, t1 = t0 + 16;
        float v0 = (t0 < NTOK) ? s[qs][0][r]*alpha : -1e30f;
        float v1 = (t1 < NTOK) ? s[qs][1][r]*alpha : -1e30f;
        float mx = fmaxf(v0, v1);
        mx = fmaxf(mx, __shfl_xor(mx,1)); mx = fmaxf(mx, __shfl_xor(mx,2));
        mx = fmaxf(mx, __shfl_xor(mx,4)); mx = fmaxf(mx, __shfl_xor(mx,8));
        float Mn  = fmaxf(mrow[qs][r], mx);
        float fac = __expf(mrow[qs][r] - Mn);
        mrow[qs][r] = Mn;
        float e0 = __expf(v0 - Mn), e1 = __expf(v1 - Mn);
        float sum = e0 + e1;
        sum += __shfl_xor(sum,1); sum += __shfl_xor(sum,2);
        sum += __shfl_xor(sum,4); sum += __shfl_xor(sum,8);
        lrow[qs][r] = lrow[qs][r]*fac + sum;
        #pragma unroll
        for (int j = 0; j < 8; j++) oacc[qs][j][r] *= fac;
        Psw[(qs*16 + quad*4 + r)*40 + l15]      = f2b(e0);
        Psw[(qs*16 + quad*4 + r)*40 + 16 + l15] = f2b(e1);
      }
    }
    bf16x8 af0 = *(const bf16x8*)&Psw[(long)l15*40 + quad*8];
    bf16x8 af1 = *(const bf16x8*)&Psw[(long)(16 + l15)*40 + quad*8];
    #pragma unroll
    for (int j = 0; j < 8; j++){
      int d = j*16 + l15;
      bf16x8 bfv = *(const bf16x8*)&Vs[(d*32 + ((c*4 + quad) ^ swz))*8];
      oacc[0][j] = __builtin_amdgcn_mfma_f32_16x16x32_bf16(af0, bfv, oacc[0][j], 0, 0, 0);
      oacc[1][j] = __builtin_amdgcn_mfma_f32_16x16x32_bf16(af1, bfv, oacc[1][j], 0, 0, 0);
    }
  }

  #pragma unroll
  for (int qs = 0; qs < 2; qs++){
    #pragma unroll
    for (int r = 0; r < 4; r++){
      int q = w*32 + qs*16 + quad*4 + r;
      if (q >= NTOK) continue;
      float invl = 1.0f / lrow[qs][r];
      ushort_t* orow = o + ((long)b*NTOK + q)*512 + hh*128;
      #pragma unroll
      for (int j = 0; j < 8; j++)
        orow[j*16 + l15] = f2b(oacc[qs][j][r]*invl);
    }
  }
}

// ---- fused (optional LN) + row-panel GEMM, K=512 fixed, B in B2 pack ----
// R6-verified chassis (512 threads, 128-row A panel in LDS, 1 block/CU) with
// two counter-driven fixes:
//  1. B register pipeline depth 2 -> 4 (pack + 4-deep never tested together;
//     2-deep exposes ~220cy of L2 latency per kc step = the 73% stall that
//     matches MfmaUtil 18%). VGPR ~164 < 256: free at 2 waves/SIMD.
//  2. LN reads LDS linearly (unit = lane, conflict-free) and absorbs the
//     stage swizzle by gathering gamma/beta at the permuted column
//     lane^(r&7) (2KB, L1-resident). Kills the 8-way LDS conflict that
//     produced SQ_LDS_BANK_CONFLICT = 3.08M.
__global__ __launch_bounds__(512, 2) void lngemm_kernel(
    const ushort_t* __restrict__ A,          // [M][512] bf16
    const ushort_t* __restrict__ Bt,         // B2-packed weights
    void* __restrict__ Cp, long ldc,
    const float* __restrict__ lng, const float* __restrict__ lnbeta,
    const float* __restrict__ bias,
    int M, int N, int flags, float alpha){
  __shared__ __align__(16) ushort_t As[128*512];   // 128 KiB
  int tid = threadIdx.x, w = tid>>6, lane = tid&63;
  int quad = lane>>4, l15 = lane&15;
  int m0 = blockIdx.x*128;

  // ---- stage A panel: unit u (16B) of row r holds global units u^(r&7) ----
  #pragma unroll
  for (int i = 0; i < 16; i++){
    int row = i*8 + w;
    int gr = m0 + row; if (gr >= M) gr = M - 1;
    const ushort_t* src = A + (long)gr*512 + ((lane ^ (row&7)) << 3);
    async_copy16(src, (void*)&As[row*512]);
  }
  __syncthreads();

  // ---- optional LayerNorm in LDS (16 rows per wave, conflict-free) ----
  if (flags & GF_LN){
    for (int j = 0; j < 16; j++){
      int r = w*16 + j;
      int cu = lane ^ (r&7);                    // global column-unit at LDS unit `lane`
      ushort_t* prow = &As[r*512 + (lane<<3)];  // linear: banks spread, no conflict
      union { uint4 v; ushort_t s[8]; } raw;
      raw.v = *(const uint4*)prow;
      float d[8];
      #pragma unroll
      for (int e = 0; e < 8; e++) d[e] = b2f(raw.s[e]);
      float s = 0.0f;
      #pragma unroll
      for (int e = 0; e < 8; e++) s += d[e];
      #pragma unroll
      for (int o = 32; o > 0; o >>= 1) s += __shfl_xor(s, o, 64);
      float mu = s * (1.0f/512.0f);
      float q = 0.0f;
      #pragma unroll
      for (int e = 0; e < 8; e++){ d[e] -= mu; q += d[e]*d[e]; }
      #pragma unroll
      for (int o = 32; o > 0; o >>= 1) q += __shfl_xor(q, o, 64);
      float rr = rsqrtf(q*(1.0f/512.0f) + 1e-5f);
      const float* gp = lng + cu*8;
      const float* bp = lnbeta + cu*8;
      float4 g0 = *(const float4*)gp, g1 = *(const float4*)(gp+4);
      float4 e0 = *(const float4*)bp, e1 = *(const float4*)(bp+4);
      float gg[8] = {g0.x,g0.y,g0.z,g0.w,g1.x,g1.y,g1.z,g1.w};
      float bb[8] = {e0.x,e0.y,e0.z,e0.w,e1.x,e1.y,e1.z,e1.w};
      ushort_t o8[8];
      #pragma unroll
      for (int e = 0; e < 8; e++) o8[e] = f2b(d[e]*rr*gg[e] + bb[e]);
      *(uint4*)prow = *(const uint4*)o8;
    }
  }
  __syncthreads();

  // ---- compute: wave tile 64x64, 256-col slabs, 4-deep B pipeline ----
  int wm = (w>>2)*64, nbw = w & 3;
  int NT = N >> 8;
  const ushort_t* Bw = Bt + (long)nbw*32768 + lane*8;   // nb = nt*4 + nbw

  bf16x8 buf[4][4];                       // [slot][j]; slot = kc&3 (static)
  #pragma unroll
  for (int s = 0; s < 4; s++)
    #pragma unroll
    for (int j = 0; j < 4; j++)
      buf[s][j] = *(const bf16x8*)(Bw + s*2048 + j*512);

  for (int nt = 0; nt < NT; nt++){
    long nxt = (nt + 1 < NT) ? 4L*32768 : 0;   // branchless cross-slab prefetch
    f32x4 acc[4][4] = {};
    #pragma unroll
    for (int kc = 0; kc < 16; kc++){
      bf16x8 af[4];
      #pragma unroll
      for (int i = 0; i < 4; i++){
        int row = wm + i*16 + l15;
        af[i] = *(const bf16x8*)&As[row*512 + (((kc*4+quad) ^ (row&7)) << 3)];
      }
      #pragma unroll
      for (int i = 0; i < 4; i++)
        #pragma unroll
        for (int j = 0; j < 4; j++)
          acc[i][j] = __builtin_amdgcn_mfma_f32_16x16x32_bf16(af[i], buf[kc&3][j], acc[i][j], 0, 0, 0);
      if (kc < 12){
        #pragma unroll
        for (int j = 0; j < 4; j++)
          buf[kc&3][j] = *(const bf16x8*)(Bw + (kc+4)*2048 + j*512);
      } else {
        #pragma unroll
        for (int j = 0; j < 4; j++)
          buf[kc&3][j] = *(const bf16x8*)(Bw + nxt + (kc-12)*2048 + j*512);
      }
    }
    // epilogue: C/D layout col=lane&15, row=quad*4+reg
    #pragma unroll
    for (int i = 0; i < 4; i++){
      int rbase = m0 + wm + i*16 + quad*4;
      #pragma unroll
      for (int j = 0; j < 4; j++){
        int gn = nt*256 + nbw*64 + j*16 + l15;
        #pragma unroll
        for (int r = 0; r < 4; r++){
          int gm = rbase + r;
          if (gm >= M) continue;
          float v = acc[i][j][r] * alpha;
          if (flags & GF_BIAS) v += bias[gn];
          if (flags & GF_ADDC) v += b2f(((const ushort_t*)Cp)[(long)gm*ldc + gn]);
          if (flags & GF_GELU) v = gelu_f(v);
          if (flags & GF_OBF16) ((ushort_t*)Cp)[(long)gm*ldc + gn] = f2b(v);
          else                  ((float*)Cp)[(long)gm*ldc + gn] = v;
        }
      }
    }
    Bw += 4L*32768;
  }
}

// ---- MFMA GEMM (head only): C = alpha*A[M,K] @ Bt[N,K]^T ----
__global__ __launch_bounds__(256) void gemm_bt_mfma(
    const ushort_t* __restrict__ A, long lda, long sA1, long sA2,
    const ushort_t* __restrict__ Bt, long ldb, long sB1, long sB2,
    void* __restrict__ Cp, long ldc, long sC1, long sC2,
    const float* __restrict__ bias, int M, int N, int K,
    int zdiv, int flags, float alpha){
  int bz = blockIdx.z;
  A  += (long)(bz/zdiv)*sA1 + (long)(bz%zdiv)*sA2;
  Bt += (long)(bz/zdiv)*sB1 + (long)(bz%zdiv)*sB2;
  long coff = (long)(bz/zdiv)*sC1 + (long)(bz%zdiv)*sC2;

  __shared__ __align__(16) ushort_t As[128*32];
  __shared__ __align__(16) ushort_t Bs[128*32];

  int tid = threadIdx.x;
  int wave = tid >> 6, lane = tid & 63;
  int quad = lane >> 4, l15 = lane & 15;
  int wm = (wave >> 1) * 64, wn = (wave & 1) * 64;
  int m0 = blockIdx.y * 128, n0 = blockIdx.x * 128;

  f32x4 acc[4][4] = {};
  bool fast = (m0 + 128 <= M) && (n0 + 128 <= N) && ((K & 31) == 0);

  if (fast){
    int rloc = wave*16 + (lane >> 2);
    int pos  = lane & 3;
    const ushort_t* A0 = A + (long)m0*lda;
    const ushort_t* B0 = Bt + (long)n0*ldb;
    for (int k0 = 0; k0 < K; k0 += 32){
      #pragma unroll
      for (int c = 0; c < 2; c++){
        int r  = c*64 + rloc;
        int cg = pos ^ ((r >> 1) & 3);
        long koff = k0 + cg*8;
        async_copy16(A0 + (long)r*lda + koff, (void*)&As[(c*256 + wave*64)*8]);
        async_copy16(B0 + (long)r*ldb + koff, (void*)&Bs[(c*256 + wave*64)*8]);
      }
      __syncthreads();
      bf16x8 af[4], bfv[4];
      #pragma unroll
      for (int i = 0; i < 4; i++){
        int row = wm + i*16 + l15;
        af[i] = *(const bf16x8*)&As[row*32 + ((quad ^ ((row>>1)&3)) << 3)];
      }
      #pragma unroll
      for (int j = 0; j < 4; j++){
        int row = wn + j*16 + l15;
        bfv[j] = *(const bf16x8*)&Bs[row*32 + ((quad ^ ((row>>1)&3)) << 3)];
      }
      #pragma unroll
      for (int i = 0; i < 4; i++)
        #pragma unroll
        for (int j = 0; j < 4; j++)
          acc[i][j] = __builtin_amdgcn_mfma_f32_16x16x32_bf16(af[i], bfv[j], acc[i][j], 0, 0, 0);
      __syncthreads();
    }
  } else {
    int nk = (K + 31) >> 5;
    for (int kt = 0; kt < nk; kt++){
      int k0 = kt << 5;
      #pragma unroll
      for (int c = 0; c < 2; c++){
        int q = c*256 + tid;
        int r = q >> 2;
        int gk = k0 + (((q & 3) ^ ((r >> 1) & 3)) << 3);
        {
          int gm = m0 + r;
          uint4 va;
          if (gm < M && gk + 8 <= K){
            va = *(const uint4*)(A + (long)gm*lda + gk);
          } else {
            ushort_t t[8];
            #pragma unroll
            for (int e = 0; e < 8; e++){
              int kk = gk + e;
              t[e] = (gm < M && kk < K) ? A[(long)gm*lda + kk] : (ushort_t)0;
            }
            va = *(const uint4*)t;
          }
          *(uint4*)&As[r*32 + (q & 3)*8] = va;
        }
        {
          int gn = n0 + r;
          uint4 vb;
          if (gn < N && gk + 8 <= K){
            vb = *(const uint4*)(Bt + (long)gn*ldb + gk);
          } else {
            ushort_t t[8];
            #pragma unroll
            for (int e = 0; e < 8; e++){
              int kk = gk + e;
              t[e] = (gn < N && kk < K) ? Bt[(long)gn*ldb + kk] : (ushort_t)0;
            }
            vb = *(const uint4*)t;
          }
          *(uint4*)&Bs[r*32 + (q & 3)*8] = vb;
        }
      }
      __syncthreads();
      bf16x8 af[4], bfv[4];
      #pragma unroll
      for (int i = 0; i < 4; i++){
        int row = wm + i*16 + l15;
        af[i] = *(const bf16x8*)&As[row*32 + ((quad ^ ((row>>1)&3)) << 3)];
      }
      #pragma unroll
      for (int j = 0; j < 4; j++){
        int row = wn + j*16 + l15;
        bfv[j] = *(const bf16x8*)&Bs[row*32 + ((quad ^ ((row>>1)&3)) << 3)];
      }
      #pragma unroll
      for (int i = 0; i < 4; i++)
        #pragma unroll
        for (int j = 0; j < 4; j++)
          acc[i][j] = __builtin_amdgcn_mfma_f32_16x16x32_bf16(af[i], bfv[j], acc[i][j], 0, 0, 0);
      __syncthreads();
    }
  }

  #pragma unroll
  for (int i = 0; i < 4; i++){
    int rbase = m0 + wm + i*16 + quad*4;
    #pragma unroll
    for (int j = 0; j < 4; j++){
      int gn = n0 + wn + j*16 + l15;
      if (gn >= N) continue;
      #pragma unroll
      for (int r = 0; r < 4; r++){
        int gm = rbase + r;
        if (gm >= M) continue;
        float v = acc[i][j][r] * alpha;
        if (flags & GF_BIAS) v += bias[gn];
        if (flags & GF_ADDC){
          if (flags & GF_OBF16) v += b2f(((const ushort_t*)Cp)[coff + (long)gm*ldc + gn]);
          else                  v += ((const float*)Cp)[coff + (long)gm*ldc + gn];
        }
        if (flags & GF_GELU) v = gelu_f(v);
        if (flags & GF_OBF16){
          ((ushort_t*)Cp)[coff + (long)gm*ldc + gn] = f2b(v);
        } else {
          ((float*)Cp)[coff + (long)gm*ldc + gn] = v;
        }
      }
    }
  }
}

__global__ void copy_cls(ushort_t* __restrict__ cat, const ushort_t* __restrict__ h,
                         int br, int b0){
  long b = blockIdx.x;
  int d = threadIdx.x;            // block 512
  cat[(b0+b)*1536 + (long)br*512 + d] = h[b*(long)NTOK*DD + d];
}

__global__ void head2_kernel(float* __restrict__ out, const float* __restrict__ hid,
                             const float* __restrict__ w2, const float* __restrict__ b2){
  __shared__ float sbuf[8];
  long b = blockIdx.x;
  float v = hid[b*DD + threadIdx.x] * w2[threadIdx.x];   // block 512
  #pragma unroll
  for (int o = 32; o > 0; o >>= 1) v += __shfl_down(v, o, 64);
  if ((threadIdx.x & 63) == 0) sbuf[threadIdx.x>>6] = v;
  __syncthreads();
  if (threadIdx.x == 0){
    float s = 0.0f;
    #pragma unroll
    for (int i = 0; i < 8; i++) s += sbuf[i];
    out[b] = 1.0f/(1.0f + expf(-(s + b2[0])));
  }
}

static size_t ws_needed(int Bc){
  auto al = [](size_t b){ return ((b + 255)/256)*256; };
  size_t BNc = (size_t)Bc*NTOK;
  size_t tot = 0;
  tot += al((12UL*1536 + 36UL*512 + 512UL)*512*2 + 512UL*1024*2); // bf16 weights (+o1)
  tot += al(BNc*DD*2);                        // h bf16 (residual)
  tot += al(BNc*DD*2);                        // z bf16
  tot += al(BNc*1536*2);                      // qkv bf16
  tot += al((size_t)Bc*NHEAD*HD*256*2);       // vt
  tot += al(128UL*1536*2) + al(128UL*512*4);  // cat bf16, hid fp32
  tot += 4096;
  return tot;
}

extern "C" void kernel_launch(void* const* d_in, const int* in_sizes, int n_in,
                              void* d_out, int out_size, void* d_ws, size_t ws_size,
                              hipStream_t stream){
  (void)in_sizes; (void)n_in; (void)out_size;
  const float* x      = (const float*)d_in[0];
  const float* w_left = (const float*)d_in[1];
  const float* b_left = (const float*)d_in[2];
  const float* w_right= (const float*)d_in[3];
  const float* b_right= (const float*)d_in[4];
  const float* w_mid  = (const float*)d_in[5];
  const float* b_mid  = (const float*)d_in[6];
  const float* pos    = (const float*)d_in[7];
  const float* cls    = (const float*)d_in[8];
  const float* ln1_g  = (const float*)d_in[9];
  const float* ln1_b  = (const float*)d_in[10];
  const float* ln2_g  = (const float*)d_in[11];
  const float* ln2_b  = (const float*)d_in[12];
  const float* wq     = (const float*)d_in[13];
  const float* wk     = (const float*)d_in[14];
  const float* wv     = (const float*)d_in[15];
  const float* wo     = (const float*)d_in[16];
  const float* fc1w   = (const float*)d_in[17];
  const float* fc1b   = (const float*)d_in[18];
  const float* fc2w   = (const float*)d_in[19];
  const float* fc2b   = (const float*)d_in[20];
  const float* o1w    = (const float*)d_in[21];
  const float* o1b    = (const float*)d_in[22];
  const float* o2w    = (const float*)d_in[23];
  const float* o2b    = (const float*)d_in[24];
  float* out = (float*)d_out;

  int Bc = 128;
  while (Bc > 1 && ws_needed(Bc) > ws_size) Bc >>= 1;
  const int nchunk = BATCH / Bc;
  const long BNc  = (long)Bc*NTOK;

  char* wsp = (char*)d_ws;
  auto carveb = [&](size_t bytes)->void*{
    void* p = (void*)wsp;
    wsp += ((bytes + 255)/256)*256;
    return p;
  };
  ushort_t* wt   = (ushort_t*)carveb((12UL*1536 + 36UL*512 + 512UL)*512*2 + 512UL*1024*2);
  ushort_t* h    = (ushort_t*)carveb(BNc*DD*2);
  ushort_t* z    = (ushort_t*)carveb(BNc*DD*2);
  ushort_t* qkv  = (ushort_t*)carveb(BNc*1536*2);
  ushort_t* vt   = (ushort_t*)carveb((size_t)Bc*NHEAD*HD*256*2);
  ushort_t* cat  = (ushort_t*)carveb(128UL*1536*2);
  float*    hid  = (float*)   carveb(128UL*512*4);

  ushort_t* wtqkv = wt;                     // B2 pack: [layer][nb24][kc][j][lane][8]
  ushort_t* wto   = wt + 12UL*1536*512;     // B2 pack: [layer][nb8][...]
  ushort_t* wt1   = wto + 12UL*512*512;
  ushort_t* wt2   = wt1 + 12UL*512*512;
  ushort_t* wth   = wt2 + 12UL*512*512;     // o1w^T: [512][1536] (row-major, head)

  {
    // B2 fragment-order pack (12 planes each). QKV interleaved per layer:
    // layer stride 1536*512; Q at nb 0..7, K at nb 8..15, V at nb 16..23.
    dim3 gp(128, 1, 12), bp(256);
    long dpq = 1536L*512, dps = 512L*512;
    wpack_kernel<<<gp,bp,0,stream>>>(wtqkv,              wq,   dpq, dps);
    wpack_kernel<<<gp,bp,0,stream>>>(wtqkv + 8L*32768,   wk,   dpq, dps);
    wpack_kernel<<<gp,bp,0,stream>>>(wtqkv + 16L*32768,  wv,   dpq, dps);
    wpack_kernel<<<gp,bp,0,stream>>>(wto,                wo,   dps, dps);
    wpack_kernel<<<gp,bp,0,stream>>>(wt1,                fc1w, dps, dps);
    wpack_kernel<<<gp,bp,0,stream>>>(wt2,                fc2w, dps, dps);
    wtrans_kernel<<<dim3(16,48,1),dim3(32,8),0,stream>>>(wth, o1w, 1536, 0, 0);
  }

  const float* wsel[3] = {w_left, w_right, w_mid};
  const float* bsel[3] = {b_left, b_right, b_mid};

  const float alpha = 0.08838834764831845f;  // 1/sqrt(128)
  int mt = (int)((BNc + 127)/128);
  dim3 gpanel(mt, 1, 1);
  dim3 gvt(4, 8, Bc*NHEAD);

  for (int br = 0; br < 3; br++){
    for (int c = 0; c < nchunk; c++){
      int b0 = c*Bc;
      embed_kernel<<<(int)BNc, 128, 0, stream>>>(h, x, wsel[br], bsel[br], pos, cls, br, b0);
      for (int l = 0; l < 4; l++){
        long wi = (long)br*4 + l;
        const float* g1 = ln1_g + wi*DD; const float* be1 = ln1_b + wi*DD;
        const float* g2 = ln2_g + wi*DD; const float* be2 = ln2_b + wi*DD;
        const ushort_t* Wqkv = wtqkv + wi*1536*512;
        const ushort_t* Wo   = wto + wi*DD*DD;
        const ushort_t* F1   = wt1 + wi*DD*DD;
        const ushort_t* F2   = wt2 + wi*DD*DD;
        const float* F1b = fc1b + wi*DD;  const float* F2b = fc2b + wi*DD;

        // qkv = LN1(h) @ Wqkv^T     (LN fused into A-panel staging)
        lngemm_kernel<<<gpanel, 512, 0, stream>>>(h, Wqkv, qkv, 1536, g1, be1,
                                                  nullptr, (int)BNc, 1536,
                                                  GF_LN|GF_OBF16, 1.0f);
        vtrans_kernel<<<gvt, dim3(32,8), 0, stream>>>(vt, qkv + 1024);
        flash_kernel<<<dim3(Bc*NHEAD), dim3(512), 0, stream>>>(z, qkv, vt, alpha);
        // h += z @ Wo^T
        lngemm_kernel<<<gpanel, 512, 0, stream>>>(z, Wo, h, 512, nullptr, nullptr,
                                                  nullptr, (int)BNc, 512,
                                                  GF_ADDC|GF_OBF16, 1.0f);
        // m = gelu(LN2(h) @ F1^T + b1)   -> qkv buffer
        lngemm_kernel<<<gpanel, 512, 0, stream>>>(h, F1, qkv, 512, g2, be2,
                                                  F1b, (int)BNc, 512,
                                                  GF_LN|GF_BIAS|GF_GELU|GF_OBF16, 1.0f);
        // h += m @ F2^T + b2
        lngemm_kernel<<<gpanel, 512, 0, stream>>>(qkv, F2, h, 512, nullptr, nullptr,
                                                  F2b, (int)BNc, 512,
                                                  GF_BIAS|GF_ADDC|GF_OBF16, 1.0f);
      }
      copy_cls<<<Bc, 512, 0, stream>>>(cat, h, br, b0);
    }
  }
  // head: hid = gelu(cat @ o1w + o1b) via MFMA (M=128,N=512,K=1536), then head2
  dim3 ghd(4, 1, 1);
  gemm_bt_mfma<<<ghd, dim3(256), 0, stream>>>(cat,1536,0,0, wth,1536,0,0, hid,DD,0,0, o1b,
                                              128,DD,1536, 1, GF_BIAS|GF_GELU, 1.0f);
  head2_kernel<<<BATCH, 512, 0, stream>>>(out, hid, o2w, o2b);
}

// Round 12
// 4664.720 us; speedup vs baseline: 1.0983x; 1.0532x over previous
//
#include <hip/hip_runtime.h>
#include <math.h>

#define DD   512
#define BATCH 128
#define NTOK 251
#define NHEAD 4
#define HD   128

#define GF_ADDC   1
#define GF_BIAS   2
#define GF_GELU   4
#define GF_OBF16  8
#define GF_LN     16

typedef unsigned short ushort_t;
typedef __attribute__((ext_vector_type(8))) short bf16x8;
typedef __attribute__((ext_vector_type(4))) float f32x4;

__constant__ int c_cols[3][12] = {
  {8,10,12,22,24,26, 9,11,13,23,25,27},
  {2, 4, 6,28,30,32, 3, 5, 7,29,31,33},
  {0,14,16,18,20, 1,15,17,19,21, 0, 0}
};
__constant__ int c_ncols[3] = {12,12,10};

__device__ __forceinline__ float gelu_f(float v){
  return 0.5f*v*(1.0f + erff(v*0.70710678118654752440f));
}
__device__ __forceinline__ ushort_t f2b(float v){   // RNE float->bf16
  union { float f; unsigned u; } x; x.f = v;
  unsigned r = x.u + 0x7fffu + ((x.u >> 16) & 1u);
  return (ushort_t)(r >> 16);
}
__device__ __forceinline__ float b2f(ushort_t u){
  union { unsigned u; float f; } x; x.u = ((unsigned)u) << 16; return x.f;
}
__device__ __forceinline__ void async_copy16(const void* g, void* l){
  __builtin_amdgcn_global_load_lds(
      (const __attribute__((address_space(1))) unsigned*)g,
      (__attribute__((address_space(3))) unsigned*)l, 16, 0, 0);
}

// ---- weight convert+transpose (head o1w only): D[n*ldD+k] = bf16(S[k*512+n]) ----
__global__ __launch_bounds__(256) void wtrans_kernel(ushort_t* __restrict__ dst,
                                                     const float* __restrict__ src,
                                                     long ldD, long dstPlane, long srcPlane){
  __shared__ float tile[32][33];
  long mat = blockIdx.z;
  const float* S = src + mat*srcPlane;
  ushort_t* D = dst + mat*dstPlane;
  int n0 = blockIdx.x*32, k0 = blockIdx.y*32;
  for (int r = threadIdx.y; r < 32; r += 8)
    tile[r][threadIdx.x] = S[(long)(k0+r)*DD + n0 + threadIdx.x];
  __syncthreads();
  for (int r = threadIdx.y; r < 32; r += 8)
    D[(long)(n0+r)*ldD + k0 + threadIdx.x] = f2b(tile[threadIdx.x][r]);
}

// ---- weight pack to MFMA-fragment order ----
// B2 layout: [nb (64-col block)][kc (0..15)][j (0..3)][lane (64)][8 bf16]
// lane=(quad<<4)|l15 holds Bt[n = nb*64 + j*16 + l15][k = kc*32 + quad*8 ..+8]
__global__ __launch_bounds__(256) void wpack_kernel(ushort_t* __restrict__ dst,
                                                    const float* __restrict__ src,
                                                    long dstPlane, long srcPlane){
  int c = blockIdx.x;                 // c = nb*16 + kc
  int nb = c >> 4, kc = c & 15;
  long mat = blockIdx.z;
  const float* S = src + mat*srcPlane;
  ushort_t* D = dst + mat*dstPlane + (long)c*2048;
  int t = threadIdx.x;
  int j = t >> 6, lane = t & 63;
  int quad = lane >> 4, l15 = lane & 15;
  int n = nb*64 + j*16 + l15;
  int k = kc*32 + quad*8;
  ushort_t o8[8];
  #pragma unroll
  for (int e = 0; e < 8; e++) o8[e] = f2b(S[(long)(k+e)*512 + n]);
  *(uint4*)(D + (j*64 + lane)*8) = *(const uint4*)o8;
}

// ---- embed -> bf16 h ----
__global__ void embed_kernel(ushort_t* __restrict__ h, const float* __restrict__ x,
                             const float* __restrict__ w, const float* __restrict__ bias,
                             const float* __restrict__ pos, const float* __restrict__ cls,
                             int br, int b0){
  long bt = blockIdx.x;
  int  t  = (int)(bt % NTOK);
  long b  = b0 + bt / NTOK;
  ushort_t* outr = h + bt*DD;
  if (t == 0){
    for (int d = threadIdx.x; d < DD; d += 128) outr[d] = f2b(cls[d] + pos[d]);
    return;
  }
  const float* xr = x + (b*(NTOK-1) + (t-1))*34;
  int nc = c_ncols[br];
  float xs[12];
  for (int j = 0; j < 12; j++) xs[j] = (j < nc) ? xr[c_cols[br][j]] : 0.0f;
  const float* posr = pos + (long)t*DD;
  for (int d = threadIdx.x; d < DD; d += 128){
    float acc = bias[d] + posr[d];
    for (int j = 0; j < nc; j++) acc = fmaf(xs[j], w[j*DD + d], acc);
    outr[d] = f2b(acc);
  }
}

// ---- V^T per (b,h): vt[plane][d][t] (ld 256, t-pad zeroed) ----
__global__ __launch_bounds__(256) void vtrans_kernel(ushort_t* __restrict__ vt,
                                                     const ushort_t* __restrict__ v){
  __shared__ ushort_t tile[32][33];
  int b = blockIdx.z >> 2, hh = blockIdx.z & 3;
  const ushort_t* src = v + (long)b*NTOK*1536 + hh*HD;
  ushort_t* dst = vt + (long)blockIdx.z*HD*256;
  int t0 = blockIdx.y*32, d0 = blockIdx.x*32;
  int tx = threadIdx.x, ty = threadIdx.y;
  for (int r = ty; r < 32; r += 8){
    int t = t0 + r;
    tile[r][tx] = (t < NTOK) ? src[(long)t*1536 + d0 + tx] : (ushort_t)0;
  }
  __syncthreads();
  for (int r = ty; r < 32; r += 8)
    dst[(long)(d0 + r)*256 + t0 + tx] = tile[tx][r];
}

// ---- fused flash attention, one block per (b,h) ----
__global__ __launch_bounds__(512, 2) void flash_kernel(
    ushort_t* __restrict__ o, const ushort_t* __restrict__ qkv,
    const ushort_t* __restrict__ vt, float alpha){
  // 16B "units": Ks[t][u], u=0..15 (row=256B); Vs[d][u], u=0..31 (row=512B)
  __shared__ __align__(16) ushort_t Ks[256*16*8];   // 64 KB
  __shared__ __align__(16) ushort_t Vs[128*32*8];   // 64 KB
  __shared__ __align__(16) ushort_t Ps[8][32*40];   // 20 KB, per-wave P
  int bh = blockIdx.x, b = bh>>2, hh = bh&3;
  const ushort_t* Qg = qkv + (long)b*NTOK*1536 + hh*HD;
  const ushort_t* Kg = Qg + 512;
  const ushort_t* Vg = vt + (long)bh*HD*256;
  int tid = threadIdx.x, w = tid>>6, lane = tid&63;
  int quad = lane>>4, l15 = lane&15;
  int swz = l15 & 7;

  bf16x8 qf[2][4];
  #pragma unroll
  for (int qs = 0; qs < 2; qs++){
    int qrow = w*32 + qs*16 + l15;
    bool qv = qrow < NTOK;
    const ushort_t* qptr = Qg + (long)qrow*1536;
    #pragma unroll
    for (int kc = 0; kc < 4; kc++)
      qf[qs][kc] = qv ? *(const bf16x8*)(qptr + kc*32 + quad*8)
                      : (bf16x8){0,0,0,0,0,0,0,0};
  }

  #pragma unroll
  for (int i = 0; i < 8; i++){
    int base = (w*8 + i)*64;
    int unit = base + lane;
    int t = unit >> 4, u = unit & 15;
    const ushort_t* src = Kg + (long)(t < NTOK ? t : 0)*1536 + ((u ^ (t&7)) << 3);
    async_copy16(src, (void*)&Ks[base*8]);
  }
  #pragma unroll
  for (int i = 0; i < 8; i++){
    int base = (w*8 + i)*64;
    int unit = base + lane;
    int d = unit >> 5, u = unit & 31;
    const ushort_t* src = Vg + (long)d*256 + ((u ^ (d&7)) << 3);
    async_copy16(src, (void*)&Vs[base*8]);
  }
  __syncthreads();

  f32x4 oacc[2][8] = {};
  float mrow[2][4], lrow[2][4];
  #pragma unroll
  for (int qs = 0; qs < 2; qs++)
    #pragma unroll
    for (int r = 0; r < 4; r++){ mrow[qs][r] = -1e30f; lrow[qs][r] = 0.0f; }

  ushort_t* Psw = &Ps[w][0];

  for (int c = 0; c < 8; c++){
    f32x4 s[2][2] = {};
    #pragma unroll
    for (int kc = 0; kc < 4; kc++){
      #pragma unroll
      for (int j = 0; j < 2; j++){
        int t = c*32 + j*16 + l15;
        bf16x8 bf = *(const bf16x8*)&Ks[(t*16 + ((kc*4 + quad) ^ swz))*8];
        s[0][j] = __builtin_amdgcn_mfma_f32_16x16x32_bf16(qf[0][kc], bf, s[0][j], 0, 0, 0);
        s[1][j] = __builtin_amdgcn_mfma_f32_16x16x32_bf16(qf[1][kc], bf, s[1][j], 0, 0, 0);
      }
    }
    #pragma unroll
    for (int qs = 0; qs < 2; qs++){
      #pragma unroll
      for (int r = 0; r < 4; r++){
        int t0 = c*32 + l15, t1 = t0 + 16;
        float v0 = (t0 < NTOK) ? s[qs][0][r]*alpha : -1e30f;
        float v1 = (t1 < NTOK) ? s[qs][1][r]*alpha : -1e30f;
        float mx = fmaxf(v0, v1);
        mx = fmaxf(mx, __shfl_xor(mx,1)); mx = fmaxf(mx, __shfl_xor(mx,2));
        mx = fmaxf(mx, __shfl_xor(mx,4)); mx = fmaxf(mx, __shfl_xor(mx,8));
        float Mn  = fmaxf(mrow[qs][r], mx);
        float fac = __expf(mrow[qs][r] - Mn);
        mrow[qs][r] = Mn;
        float e0 = __expf(v0 - Mn), e1 = __expf(v1 - Mn);
        float sum = e0 + e1;
        sum += __shfl_xor(sum,1); sum += __shfl_xor(sum,2);
        sum += __shfl_xor(sum,4); sum += __shfl_xor(sum,8);
        lrow[qs][r] = lrow[qs][r]*fac + sum;
        #pragma unroll
        for (int j = 0; j < 8; j++) oacc[qs][j][r] *= fac;
        Psw[(qs*16 + quad*4 + r)*40 + l15]      = f2b(e0);
        Psw[(qs*16 + quad*4 + r)*40 + 16 + l15] = f2b(e1);
      }
    }
    bf16x8 af0 = *(const bf16x8*)&Psw[(long)l15*40 + quad*8];
    bf16x8 af1 = *(const bf16x8*)&Psw[(long)(16 + l15)*40 + quad*8];
    #pragma unroll
    for (int j = 0; j < 8; j++){
      int d = j*16 + l15;
      bf16x8 bfv = *(const bf16x8*)&Vs[(d*32 + ((c*4 + quad) ^ swz))*8];
      oacc[0][j] = __builtin_amdgcn_mfma_f32_16x16x32_bf16(af0, bfv, oacc[0][j], 0, 0, 0);
      oacc[1][j] = __builtin_amdgcn_mfma_f32_16x16x32_bf16(af1, bfv, oacc[1][j], 0, 0, 0);
    }
  }

  #pragma unroll
  for (int qs = 0; qs < 2; qs++){
    #pragma unroll
    for (int r = 0; r < 4; r++){
      int q = w*32 + qs*16 + quad*4 + r;
      if (q >= NTOK) continue;
      float invl = 1.0f / lrow[qs][r];
      ushort_t* orow = o + ((long)b*NTOK + q)*512 + hh*128;
      #pragma unroll
      for (int j = 0; j < 8; j++)
        orow[j*16 + l15] = f2b(oacc[qs][j][r]*invl);
    }
  }
}

// ---- fused (optional LN) + row-panel GEMM, K=512 fixed, B in B2 pack ----
// 512 threads, 128-row A panel in LDS, 1 block/CU, 4-deep register B
// pipeline from the fragment-ordered B2 pack, conflict-free LN (linear LDS
// unit, gamma/beta gathered at the permuted column).
__global__ __launch_bounds__(512, 2) void lngemm_kernel(
    const ushort_t* __restrict__ A,          // [M][512] bf16
    const ushort_t* __restrict__ Bt,         // B2-packed weights
    void* __restrict__ Cp, long ldc,
    const float* __restrict__ lng, const float* __restrict__ lnbeta,
    const float* __restrict__ bias,
    int M, int N, int flags, float alpha){
  __shared__ __align__(16) ushort_t As[128*512];   // 128 KiB
  int tid = threadIdx.x, w = tid>>6, lane = tid&63;
  int quad = lane>>4, l15 = lane&15;
  int m0 = blockIdx.x*128;

  // ---- stage A panel: unit u (16B) of row r holds global units u^(r&7) ----
  #pragma unroll
  for (int i = 0; i < 16; i++){
    int row = i*8 + w;
    int gr = m0 + row; if (gr >= M) gr = M - 1;
    const ushort_t* src = A + (long)gr*512 + ((lane ^ (row&7)) << 3);
    async_copy16(src, (void*)&As[row*512]);
  }
  __syncthreads();

  // ---- optional LayerNorm in LDS (16 rows per wave, conflict-free) ----
  if (flags & GF_LN){
    for (int j = 0; j < 16; j++){
      int r = w*16 + j;
      int cu = lane ^ (r&7);                    // global column-unit at LDS unit `lane`
      ushort_t* prow = &As[r*512 + (lane<<3)];  // linear: banks spread, no conflict
      union { uint4 v; ushort_t s[8]; } raw;
      raw.v = *(const uint4*)prow;
      float d[8];
      #pragma unroll
      for (int e = 0; e < 8; e++) d[e] = b2f(raw.s[e]);
      float s = 0.0f;
      #pragma unroll
      for (int e = 0; e < 8; e++) s += d[e];
      #pragma unroll
      for (int o = 32; o > 0; o >>= 1) s += __shfl_xor(s, o, 64);
      float mu = s * (1.0f/512.0f);
      float q = 0.0f;
      #pragma unroll
      for (int e = 0; e < 8; e++){ d[e] -= mu; q += d[e]*d[e]; }
      #pragma unroll
      for (int o = 32; o > 0; o >>= 1) q += __shfl_xor(q, o, 64);
      float rr = rsqrtf(q*(1.0f/512.0f) + 1e-5f);
      const float* gp = lng + cu*8;
      const float* bp = lnbeta + cu*8;
      float4 g0 = *(const float4*)gp, g1 = *(const float4*)(gp+4);
      float4 e0 = *(const float4*)bp, e1 = *(const float4*)(bp+4);
      float gg[8] = {g0.x,g0.y,g0.z,g0.w,g1.x,g1.y,g1.z,g1.w};
      float bb[8] = {e0.x,e0.y,e0.z,e0.w,e1.x,e1.y,e1.z,e1.w};
      ushort_t o8[8];
      #pragma unroll
      for (int e = 0; e < 8; e++) o8[e] = f2b(d[e]*rr*gg[e] + bb[e]);
      *(uint4*)prow = *(const uint4*)o8;
    }
  }
  __syncthreads();

  // ---- compute: wave tile 64x64, 256-col slabs, 4-deep B pipeline ----
  int wm = (w>>2)*64, nbw = w & 3;
  int NT = N >> 8;
  const ushort_t* Bw = Bt + (long)nbw*32768 + lane*8;   // nb = nt*4 + nbw

  bf16x8 buf[4][4];                       // [slot][j]; slot = kc&3 (static)
  #pragma unroll
  for (int s = 0; s < 4; s++)
    #pragma unroll
    for (int j = 0; j < 4; j++)
      buf[s][j] = *(const bf16x8*)(Bw + s*2048 + j*512);

  for (int nt = 0; nt < NT; nt++){
    long nxt = (nt + 1 < NT) ? 4L*32768 : 0;   // branchless cross-slab prefetch
    f32x4 acc[4][4] = {};
    #pragma unroll
    for (int kc = 0; kc < 16; kc++){
      bf16x8 af[4];
      #pragma unroll
      for (int i = 0; i < 4; i++){
        int row = wm + i*16 + l15;
        af[i] = *(const bf16x8*)&As[row*512 + (((kc*4+quad) ^ (row&7)) << 3)];
      }
      #pragma unroll
      for (int i = 0; i < 4; i++)
        #pragma unroll
        for (int j = 0; j < 4; j++)
          acc[i][j] = __builtin_amdgcn_mfma_f32_16x16x32_bf16(af[i], buf[kc&3][j], acc[i][j], 0, 0, 0);
      if (kc < 12){
        #pragma unroll
        for (int j = 0; j < 4; j++)
          buf[kc&3][j] = *(const bf16x8*)(Bw + (kc+4)*2048 + j*512);
      } else {
        #pragma unroll
        for (int j = 0; j < 4; j++)
          buf[kc&3][j] = *(const bf16x8*)(Bw + nxt + (kc-12)*2048 + j*512);
      }
    }
    // epilogue: C/D layout col=lane&15, row=quad*4+reg
    #pragma unroll
    for (int i = 0; i < 4; i++){
      int rbase = m0 + wm + i*16 + quad*4;
      #pragma unroll
      for (int j = 0; j < 4; j++){
        int gn = nt*256 + nbw*64 + j*16 + l15;
        #pragma unroll
        for (int r = 0; r < 4; r++){
          int gm = rbase + r;
          if (gm >= M) continue;
          float v = acc[i][j][r] * alpha;
          if (flags & GF_BIAS) v += bias[gn];
          if (flags & GF_ADDC) v += b2f(((const ushort_t*)Cp)[(long)gm*ldc + gn]);
          if (flags & GF_GELU) v = gelu_f(v);
          if (flags & GF_OBF16) ((ushort_t*)Cp)[(long)gm*ldc + gn] = f2b(v);
          else                  ((float*)Cp)[(long)gm*ldc + gn] = v;
        }
      }
    }
    Bw += 4L*32768;
  }
}

// ---- MFMA GEMM (head partials): C = alpha*A[M,K] @ Bt[N,K]^T ----
__global__ __launch_bounds__(256) void gemm_bt_mfma(
    const ushort_t* __restrict__ A, long lda, long sA1, long sA2,
    const ushort_t* __restrict__ Bt, long ldb, long sB1, long sB2,
    void* __restrict__ Cp, long ldc, long sC1, long sC2,
    const float* __restrict__ bias, int M, int N, int K,
    int zdiv, int flags, float alpha){
  int bz = blockIdx.z;
  A  += (long)(bz/zdiv)*sA1 + (long)(bz%zdiv)*sA2;
  Bt += (long)(bz/zdiv)*sB1 + (long)(bz%zdiv)*sB2;
  long coff = (long)(bz/zdiv)*sC1 + (long)(bz%zdiv)*sC2;

  __shared__ __align__(16) ushort_t As[128*32];
  __shared__ __align__(16) ushort_t Bs[128*32];

  int tid = threadIdx.x;
  int wave = tid >> 6, lane = tid & 63;
  int quad = lane >> 4, l15 = lane & 15;
  int wm = (wave >> 1) * 64, wn = (wave & 1) * 64;
  int m0 = blockIdx.y * 128, n0 = blockIdx.x * 128;

  f32x4 acc[4][4] = {};
  bool fast = (m0 + 128 <= M) && (n0 + 128 <= N) && ((K & 31) == 0);

  if (fast){
    int rloc = wave*16 + (lane >> 2);
    int pos  = lane & 3;
    const ushort_t* A0 = A + (long)m0*lda;
    const ushort_t* B0 = Bt + (long)n0*ldb;
    for (int k0 = 0; k0 < K; k0 += 32){
      #pragma unroll
      for (int c = 0; c < 2; c++){
        int r  = c*64 + rloc;
        int cg = pos ^ ((r >> 1) & 3);
        long koff = k0 + cg*8;
        async_copy16(A0 + (long)r*lda + koff, (void*)&As[(c*256 + wave*64)*8]);
        async_copy16(B0 + (long)r*ldb + koff, (void*)&Bs[(c*256 + wave*64)*8]);
      }
      __syncthreads();
      bf16x8 af[4], bfv[4];
      #pragma unroll
      for (int i = 0; i < 4; i++){
        int row = wm + i*16 + l15;
        af[i] = *(const bf16x8*)&As[row*32 + ((quad ^ ((row>>1)&3)) << 3)];
      }
      #pragma unroll
      for (int j = 0; j < 4; j++){
        int row = wn + j*16 + l15;
        bfv[j] = *(const bf16x8*)&Bs[row*32 + ((quad ^ ((row>>1)&3)) << 3)];
      }
      #pragma unroll
      for (int i = 0; i < 4; i++)
        #pragma unroll
        for (int j = 0; j < 4; j++)
          acc[i][j] = __builtin_amdgcn_mfma_f32_16x16x32_bf16(af[i], bfv[j], acc[i][j], 0, 0, 0);
      __syncthreads();
    }
  } else {
    int nk = (K + 31) >> 5;
    for (int kt = 0; kt < nk; kt++){
      int k0 = kt << 5;
      #pragma unroll
      for (int c = 0; c < 2; c++){
        int q = c*256 + tid;
        int r = q >> 2;
        int gk = k0 + (((q & 3) ^ ((r >> 1) & 3)) << 3);
        {
          int gm = m0 + r;
          uint4 va;
          if (gm < M && gk + 8 <= K){
            va = *(const uint4*)(A + (long)gm*lda + gk);
          } else {
            ushort_t t[8];
            #pragma unroll
            for (int e = 0; e < 8; e++){
              int kk = gk + e;
              t[e] = (gm < M && kk < K) ? A[(long)gm*lda + kk] : (ushort_t)0;
            }
            va = *(const uint4*)t;
          }
          *(uint4*)&As[r*32 + (q & 3)*8] = va;
        }
        {
          int gn = n0 + r;
          uint4 vb;
          if (gn < N && gk + 8 <= K){
            vb = *(const uint4*)(Bt + (long)gn*ldb + gk);
          } else {
            ushort_t t[8];
            #pragma unroll
            for (int e = 0; e < 8; e++){
              int kk = gk + e;
              t[e] = (gn < N && kk < K) ? Bt[(long)gn*ldb + kk] : (ushort_t)0;
            }
            vb = *(const uint4*)t;
          }
          *(uint4*)&Bs[r*32 + (q & 3)*8] = vb;
        }
      }
      __syncthreads();
      bf16x8 af[4], bfv[4];
      #pragma unroll
      for (int i = 0; i < 4; i++){
        int row = wm + i*16 + l15;
        af[i] = *(const bf16x8*)&As[row*32 + ((quad ^ ((row>>1)&3)) << 3)];
      }
      #pragma unroll
      for (int j = 0; j < 4; j++){
        int row = wn + j*16 + l15;
        bfv[j] = *(const bf16x8*)&Bs[row*32 + ((quad ^ ((row>>1)&3)) << 3)];
      }
      #pragma unroll
      for (int i = 0; i < 4; i++)
        #pragma unroll
        for (int j = 0; j < 4; j++)
          acc[i][j] = __builtin_amdgcn_mfma_f32_16x16x32_bf16(af[i], bfv[j], acc[i][j], 0, 0, 0);
      __syncthreads();
    }
  }

  #pragma unroll
  for (int i = 0; i < 4; i++){
    int rbase = m0 + wm + i*16 + quad*4;
    #pragma unroll
    for (int j = 0; j < 4; j++){
      int gn = n0 + wn + j*16 + l15;
      if (gn >= N) continue;
      #pragma unroll
      for (int r = 0; r < 4; r++){
        int gm = rbase + r;
        if (gm >= M) continue;
        float v = acc[i][j][r] * alpha;
        if (flags & GF_BIAS) v += bias[gn];
        if (flags & GF_ADDC){
          if (flags & GF_OBF16) v += b2f(((const ushort_t*)Cp)[coff + (long)gm*ldc + gn]);
          else                  v += ((const float*)Cp)[coff + (long)gm*ldc + gn];
        }
        if (flags & GF_GELU) v = gelu_f(v);
        if (flags & GF_OBF16){
          ((ushort_t*)Cp)[coff + (long)gm*ldc + gn] = f2b(v);
        } else {
          ((float*)Cp)[coff + (long)gm*ldc + gn] = v;
        }
      }
    }
  }
}

__global__ void copy_cls(ushort_t* __restrict__ cat, const ushort_t* __restrict__ h,
                         int br, int b0){
  long b = blockIdx.x;
  int d = threadIdx.x;            // block 512
  cat[(b0+b)*1536 + (long)br*512 + d] = h[b*(long)NTOK*DD + d];
}

// ---- head tail: sum 12 K-partials, +bias, gelu, dot w2, sigmoid ----
__global__ void head2_kernel(float* __restrict__ out, const float* __restrict__ part,
                             const float* __restrict__ o1b,
                             const float* __restrict__ w2, const float* __restrict__ b2){
  __shared__ float sbuf[8];
  long b = blockIdx.x;
  int d = threadIdx.x;                            // block 512
  float s12 = 0.0f;
  #pragma unroll
  for (int p = 0; p < 12; p++) s12 += part[(long)p*128*512 + b*512 + d];
  float v = gelu_f(s12 + o1b[d]) * w2[d];
  #pragma unroll
  for (int o = 32; o > 0; o >>= 1) v += __shfl_down(v, o, 64);
  if ((threadIdx.x & 63) == 0) sbuf[threadIdx.x>>6] = v;
  __syncthreads();
  if (threadIdx.x == 0){
    float s = 0.0f;
    #pragma unroll
    for (int i = 0; i < 8; i++) s += sbuf[i];
    out[b] = 1.0f/(1.0f + expf(-(s + b2[0])));
  }
}

static size_t ws_needed(int Bc){
  auto al = [](size_t b){ return ((b + 255)/256)*256; };
  size_t BNc = (size_t)Bc*NTOK;
  size_t tot = 0;
  tot += al((12UL*1536 + 36UL*512 + 512UL)*512*2 + 512UL*1024*2); // bf16 weights (+o1)
  tot += al(BNc*DD*2);                        // h bf16 (residual)
  tot += al(BNc*DD*2);                        // z bf16
  tot += al(BNc*1536*2);                      // qkv bf16
  tot += al((size_t)Bc*NHEAD*HD*256*2);       // vt
  tot += al(128UL*1536*2) + al(12UL*128*512*4); // cat bf16, part fp32
  tot += 4096;
  return tot;
}

extern "C" void kernel_launch(void* const* d_in, const int* in_sizes, int n_in,
                              void* d_out, int out_size, void* d_ws, size_t ws_size,
                              hipStream_t stream){
  (void)in_sizes; (void)n_in; (void)out_size;
  const float* x      = (const float*)d_in[0];
  const float* w_left = (const float*)d_in[1];
  const float* b_left = (const float*)d_in[2];
  const float* w_right= (const float*)d_in[3];
  const float* b_right= (const float*)d_in[4];
  const float* w_mid  = (const float*)d_in[5];
  const float* b_mid  = (const float*)d_in[6];
  const float* pos    = (const float*)d_in[7];
  const float* cls    = (const float*)d_in[8];
  const float* ln1_g  = (const float*)d_in[9];
  const float* ln1_b  = (const float*)d_in[10];
  const float* ln2_g  = (const float*)d_in[11];
  const float* ln2_b  = (const float*)d_in[12];
  const float* wq     = (const float*)d_in[13];
  const float* wk     = (const float*)d_in[14];
  const float* wv     = (const float*)d_in[15];
  const float* wo     = (const float*)d_in[16];
  const float* fc1w   = (const float*)d_in[17];
  const float* fc1b   = (const float*)d_in[18];
  const float* fc2w   = (const float*)d_in[19];
  const float* fc2b   = (const float*)d_in[20];
  const float* o1w    = (const float*)d_in[21];
  const float* o1b    = (const float*)d_in[22];
  const float* o2w    = (const float*)d_in[23];
  const float* o2b    = (const float*)d_in[24];
  float* out = (float*)d_out;

  int Bc = 128;
  while (Bc > 1 && ws_needed(Bc) > ws_size) Bc >>= 1;
  const int nchunk = BATCH / Bc;
  const long BNc  = (long)Bc*NTOK;

  char* wsp = (char*)d_ws;
  auto carveb = [&](size_t bytes)->void*{
    void* p = (void*)wsp;
    wsp += ((bytes + 255)/256)*256;
    return p;
  };
  ushort_t* wt   = (ushort_t*)carveb((12UL*1536 + 36UL*512 + 512UL)*512*2 + 512UL*1024*2);
  ushort_t* h    = (ushort_t*)carveb(BNc*DD*2);
  ushort_t* z    = (ushort_t*)carveb(BNc*DD*2);
  ushort_t* qkv  = (ushort_t*)carveb(BNc*1536*2);
  ushort_t* vt   = (ushort_t*)carveb((size_t)Bc*NHEAD*HD*256*2);
  ushort_t* cat  = (ushort_t*)carveb(128UL*1536*2);
  float*    part = (float*)   carveb(12UL*128*512*4);

  ushort_t* wtqkv = wt;                     // B2 pack: [layer][nb24][kc][j][lane][8]
  ushort_t* wto   = wt + 12UL*1536*512;     // B2 pack: [layer][nb8][...]
  ushort_t* wt1   = wto + 12UL*512*512;
  ushort_t* wt2   = wt1 + 12UL*512*512;
  ushort_t* wth   = wt2 + 12UL*512*512;     // o1w^T: [512][1536] (row-major, head)

  {
    // B2 fragment-order pack (12 planes each). QKV interleaved per layer:
    // layer stride 1536*512; Q at nb 0..7, K at nb 8..15, V at nb 16..23.
    dim3 gp(128, 1, 12), bp(256);
    long dpq = 1536L*512, dps = 512L*512;
    wpack_kernel<<<gp,bp,0,stream>>>(wtqkv,              wq,   dpq, dps);
    wpack_kernel<<<gp,bp,0,stream>>>(wtqkv + 8L*32768,   wk,   dpq, dps);
    wpack_kernel<<<gp,bp,0,stream>>>(wtqkv + 16L*32768,  wv,   dpq, dps);
    wpack_kernel<<<gp,bp,0,stream>>>(wto,                wo,   dps, dps);
    wpack_kernel<<<gp,bp,0,stream>>>(wt1,                fc1w, dps, dps);
    wpack_kernel<<<gp,bp,0,stream>>>(wt2,                fc2w, dps, dps);
    wtrans_kernel<<<dim3(16,48,1),dim3(32,8),0,stream>>>(wth, o1w, 1536, 0, 0);
  }

  const float* wsel[3] = {w_left, w_right, w_mid};
  const float* bsel[3] = {b_left, b_right, b_mid};

  const float alpha = 0.08838834764831845f;  // 1/sqrt(128)
  int mt = (int)((BNc + 127)/128);
  dim3 gpanel(mt, 1, 1);
  dim3 gvt(4, 8, Bc*NHEAD);

  for (int br = 0; br < 3; br++){
    for (int c = 0; c < nchunk; c++){
      int b0 = c*Bc;
      embed_kernel<<<(int)BNc, 128, 0, stream>>>(h, x, wsel[br], bsel[br], pos, cls, br, b0);
      for (int l = 0; l < 4; l++){
        long wi = (long)br*4 + l;
        const float* g1 = ln1_g + wi*DD; const float* be1 = ln1_b + wi*DD;
        const float* g2 = ln2_g + wi*DD; const float* be2 = ln2_b + wi*DD;
        const ushort_t* Wqkv = wtqkv + wi*1536*512;
        const ushort_t* Wo   = wto + wi*DD*DD;
        const ushort_t* F1   = wt1 + wi*DD*DD;
        const ushort_t* F2   = wt2 + wi*DD*DD;
        const float* F1b = fc1b + wi*DD;  const float* F2b = fc2b + wi*DD;

        // qkv = LN1(h) @ Wqkv^T     (LN fused into A-panel staging)
        lngemm_kernel<<<gpanel, 512, 0, stream>>>(h, Wqkv, qkv, 1536, g1, be1,
                                                  nullptr, (int)BNc, 1536,
                                                  GF_LN|GF_OBF16, 1.0f);
        vtrans_kernel<<<gvt, dim3(32,8), 0, stream>>>(vt, qkv + 1024);
        flash_kernel<<<dim3(Bc*NHEAD), dim3(512), 0, stream>>>(z, qkv, vt, alpha);
        // h += z @ Wo^T
        lngemm_kernel<<<gpanel, 512, 0, stream>>>(z, Wo, h, 512, nullptr, nullptr,
                                                  nullptr, (int)BNc, 512,
                                                  GF_ADDC|GF_OBF16, 1.0f);
        // m = gelu(LN2(h) @ F1^T + b1)   -> qkv buffer
        lngemm_kernel<<<gpanel, 512, 0, stream>>>(h, F1, qkv, 512, g2, be2,
                                                  F1b, (int)BNc, 512,
                                                  GF_LN|GF_BIAS|GF_GELU|GF_OBF16, 1.0f);
        // h += m @ F2^T + b2
        lngemm_kernel<<<gpanel, 512, 0, stream>>>(qkv, F2, h, 512, nullptr, nullptr,
                                                  F2b, (int)BNc, 512,
                                                  GF_BIAS|GF_ADDC|GF_OBF16, 1.0f);
      }
      copy_cls<<<Bc, 512, 0, stream>>>(cat, h, br, b0);
    }
  }
  // head: K-split GEMM partials part[p] = cat[:, p*128:(p+1)*128] @ o1w[p*128...]
  // grid (4 N-tiles x 12 K-chunks) = 48 blocks, 4 k-steps each (was 4 blocks
  // x 48 serial barrier-drain steps at ~0% occupancy = 155 us).
  dim3 ghd(4, 1, 12);
  gemm_bt_mfma<<<ghd, dim3(256), 0, stream>>>(cat,1536,0,128, wth,1536,0,128,
                                              part,512, 0, 128L*512, nullptr,
                                              128,DD,128, 12, 0, 1.0f);
  head2_kernel<<<BATCH, 512, 0, stream>>>(out, part, o1b, o2w, o2b);
}